// Round 18
// baseline (834.200 us; speedup 1.0000x reference)
//
#include <hip/hip_runtime.h>
#include <stdint.h>

static constexpr int kB = 8, kS = 2048, kD = 1024, kF = 4096, kE = 8, kC = 512;

typedef unsigned short u16;
typedef __attribute__((ext_vector_type(8))) short bf16x8;
typedef __attribute__((ext_vector_type(4))) float f32x4;

__device__ __forceinline__ u16 f2bf(float f) {
    union { float f; uint32_t u; } v; v.f = f;
    return (u16)((v.u + 0x7fffu + ((v.u >> 16) & 1u)) >> 16);
}
__device__ __forceinline__ void gload16(const u16* g, u16* l) {
    __builtin_amdgcn_global_load_lds(
        (__attribute__((address_space(1))) void*)(u16*)g,
        (__attribute__((address_space(3))) void*)l, 16, 0, 0);
}

static constexpr int kSmemBytes = 132096;  // A 64KB + B 64KB + slots 1KB

// ---------------- init: zero page (+ full out sweep for fallback tiers); resets ndrop -------
__global__ void init_k(uint4* __restrict__ outz, uint4* __restrict__ zb,
                       int* __restrict__ ndropp, int sweep) {
    if (blockIdx.x == 0 && threadIdx.x == 0 && ndropp) *ndropp = 0;
    if (blockIdx.x == 0 && zb && threadIdx.x < 256) zb[threadIdx.x] = (uint4){0, 0, 0, 0};
    if (!sweep) return;
    const size_t n = (size_t)kB * kS * kD * 4 / 16;
    size_t stride = (size_t)gridDim.x * blockDim.x;
    for (size_t i = (size_t)blockIdx.x * blockDim.x + threadIdx.x; i < n; i += stride)
        outz[i] = (uint4){0, 0, 0, 0};
}

// ---------------- zero only dropped-token rows of out ----------------
__global__ void zdrop_k(const int* __restrict__ droplist, const int* __restrict__ ndropp,
                        float4* __restrict__ outp) {
    int nd = *ndropp;
    size_t total = (size_t)nd * (kD / 4);
    size_t stride = (size_t)gridDim.x * blockDim.x;
    for (size_t i = (size_t)blockIdx.x * blockDim.x + threadIdx.x; i < total; i += stride) {
        int row = droplist[i >> 8];       // kD/4 = 256 float4 per row
        int col = (int)(i & 255);
        outp[(size_t)row * 256 + col] = (float4){0.f, 0.f, 0.f, 0.f};
    }
}

// ---------------- router (fused): fp32 logits + argmax + writes bf16 hidden image ----------
__global__ __launch_bounds__(256) void router_k(
    const float* __restrict__ hidden, const float* __restrict__ rw,
    float* __restrict__ logits_out, int* __restrict__ expert_id, float* __restrict__ maxprob,
    u16* __restrict__ hbf)
{
    int token = blockIdx.x * 4 + (threadIdx.x >> 6);
    int lane = threadIdx.x & 63;
    const float* hrow = hidden + (size_t)token * kD;
    float acc[8] = {0, 0, 0, 0, 0, 0, 0, 0};
    for (int d0 = lane * 4; d0 < kD; d0 += 256) {
        float4 h4 = *(const float4*)(hrow + d0);
        float hv[4] = {h4.x, h4.y, h4.z, h4.w};
        if (hbf) {
            u16 t4[4] = {f2bf(h4.x), f2bf(h4.y), f2bf(h4.z), f2bf(h4.w)};
            *(uint2*)(hbf + (size_t)token * kD + d0) = *(const uint2*)t4;
        }
        #pragma unroll
        for (int j = 0; j < 4; j++) {
            const float* wr = rw + (size_t)(d0 + j) * 8;
            float4 w0 = *(const float4*)wr, w1 = *(const float4*)(wr + 4);
            acc[0] += hv[j] * w0.x; acc[1] += hv[j] * w0.y;
            acc[2] += hv[j] * w0.z; acc[3] += hv[j] * w0.w;
            acc[4] += hv[j] * w1.x; acc[5] += hv[j] * w1.y;
            acc[6] += hv[j] * w1.z; acc[7] += hv[j] * w1.w;
        }
    }
    #pragma unroll
    for (int off = 32; off >= 1; off >>= 1) {
        #pragma unroll
        for (int e = 0; e < 8; e++) acc[e] += __shfl_down(acc[e], off, 64);
    }
    if (lane == 0) {
        float m = acc[0];
        #pragma unroll
        for (int e = 1; e < 8; e++) m = fmaxf(m, acc[e]);
        float ex[8], s = 0.f;
        #pragma unroll
        for (int e = 0; e < 8; e++) { ex[e] = expf(acc[e] - m); s += ex[e]; }
        int best = 0; float bv = -1.f;
        #pragma unroll
        for (int e = 0; e < 8; e++) {
            float p = ex[e] / s;
            if (p > bv) { bv = p; best = e; }
            logits_out[(size_t)token * 8 + e] = acc[e];
        }
        expert_id[token] = best;
        maxprob[token] = bv;
    }
}

// ---------------- capacity scan (+ dropped-token list for targeted zeroing) ----------------
__global__ __launch_bounds__(64) void scan_k(
    const int* __restrict__ expert_id, int* __restrict__ slot_token,
    int* __restrict__ counts, float* __restrict__ expidx_out,
    int* __restrict__ droplist, int* __restrict__ ndropp)
{
    __shared__ int eids[kS];
    int b = blockIdx.x, tid = threadIdx.x;
    for (int s = tid; s < kS; s += 64) eids[s] = expert_id[b * kS + s];
    __syncthreads();
    if (tid < kE) {
        int e = tid, cnt = 0;
        for (int s = 0; s < kS; s++) {
            if (eids[s] == e) {
                if (cnt < kC) {
                    slot_token[(b * kE + e) * kC + cnt] = s;
                    expidx_out[b * kS + s] = (float)e;
                    cnt++;
                } else {
                    expidx_out[b * kS + s] = 0.f;
                    if (droplist) {
                        int di = atomicAdd(ndropp, 1);
                        droplist[di] = (b << 11) | s;
                    }
                }
            }
        }
        counts[b * kE + e] = cnt;
        for (int c = cnt; c < kC; c++) slot_token[(b * kE + e) * kC + c] = -1;
    }
}

// ---------------- build: pack experts across batches; gslot[e][i] = b*2048+s (-1 pad) ------
__global__ __launch_bounds__(256) void build_k(
    const int* __restrict__ counts, const int* __restrict__ slot_token,
    int* __restrict__ gslot, int* __restrict__ glist, int* __restrict__ ngp)
{
    __shared__ int offs[kE][kB];
    __shared__ int tiles[kE];
    int tid = threadIdx.x;
    if (tid < kE) {
        int e = tid, o = 0;
        #pragma unroll
        for (int b = 0; b < kB; b++) { offs[e][b] = o; o += counts[b * kE + e]; }
        tiles[e] = (o + 255) >> 8;
    }
    __syncthreads();
    for (int e = 0; e < kE; e++) {
        int padded = tiles[e] << 8;
        for (int i = tid; i < padded; i += 256) gslot[e * (kB * kC) + i] = -1;
    }
    __syncthreads();
    for (int e = 0; e < kE; e++)
        for (int b = 0; b < kB; b++) {
            int cnt = counts[b * kE + e], base = offs[e][b];
            for (int c = tid; c < cnt; c += 256)
                gslot[e * (kB * kC) + base + c] = (b << 11) | slot_token[(b * kE + e) * kC + c];
        }
    if (tid == 0) {
        int n = 0;
        for (int e = 0; e < kE; e++)
            for (int t = 0; t < tiles[e]; t++) glist[n++] = (e << 8) | t;
        *ngp = n;
    }
}

// ---------------- vectorized convert-transpose: fp32 [R][Cn] -> bf16 [Cn][R] ----------------
__global__ __launch_bounds__(256) void transpose_v(
    const float* __restrict__ src, u16* __restrict__ dst, int R, int Cn)
{
    __shared__ u16 tl[64][68];
    size_t eo = (size_t)blockIdx.z * R * Cn;
    int c0 = blockIdx.x * 64, r0 = blockIdx.y * 64;
    int t = threadIdx.x;
    int tx = t & 15, ty = t >> 4;
    #pragma unroll
    for (int i = 0; i < 4; i++) {
        int r = ty + 16 * i;
        float4 v = *(const float4*)(src + eo + (size_t)(r0 + r) * Cn + c0 + tx * 4);
        tl[tx * 4 + 0][r] = f2bf(v.x);
        tl[tx * 4 + 1][r] = f2bf(v.y);
        tl[tx * 4 + 2][r] = f2bf(v.z);
        tl[tx * 4 + 3][r] = f2bf(v.w);
    }
    __syncthreads();
    int seg = t & 7, clb = t >> 3;
    #pragma unroll
    for (int ii = 0; ii < 2; ii++) {
        int cl = clb + 32 * ii;
        uint4 v = *(const uint4*)&tl[cl][seg * 8];
        *(uint4*)(dst + eo + (size_t)(c0 + cl) * R + r0 + seg * 8) = v;
    }
}

// ================= 8-phase 256x256 MFMA GEMM, persistent + XCD-affine packed queue ==========
// XCD mapping: tile t -> XCD (t%8); its 32 blocks (bid%8==x) run the tile's nt-sharers in the
// same round on the same L2 (A/H panel fetched once per XCD).
#define SA8(kt, kh) { int off_ = (((kt) & 1) << 14) + ((kh) << 13); int go_ = (kt) * 64 + (kh) * 32; \
    gload16(sA0 + go_, dA + off_); gload16(sA1 + go_, dA + off_ + 512); }
#define SB8(kt, kh) { int off_ = (((kt) & 1) << 14) + ((kh) << 13); int go_ = (kt) * 64 + (kh) * 32; \
    gload16(sB0 + go_, dB + off_); gload16(sB1 + go_, dB + off_ + 512); }
#define RDA03(buf, kh) { const u16* a_ = rA + ((buf) << 14) + ((kh) << 13); \
    const u16* b_ = rB + ((buf) << 14) + ((kh) << 13); \
    _Pragma("unroll") for (int m_ = 0; m_ < 4; m_++) af[m_] = *(const bf16x8*)(a_ + m_ * 512); \
    _Pragma("unroll") for (int n_ = 0; n_ < 4; n_++) bfr[n_] = *(const bf16x8*)(b_ + n_ * 512); }
#define RDA47(buf, kh) { const u16* a_ = rA + ((buf) << 14) + ((kh) << 13); \
    _Pragma("unroll") for (int m_ = 4; m_ < 8; m_++) af[m_] = *(const bf16x8*)(a_ + m_ * 512); }
#define MM8(mlo) { _Pragma("unroll") for (int m_ = 0; m_ < 4; m_++) \
    { _Pragma("unroll") for (int n_ = 0; n_ < 4; n_++) \
      acc[(mlo) + m_][n_] = __builtin_amdgcn_mfma_f32_16x16x32_bf16(af[(mlo) + m_], bfr[n_], acc[(mlo) + m_][n_], 0, 0, 0); } }
#define PH_MID() __builtin_amdgcn_sched_barrier(0); __builtin_amdgcn_s_barrier(); \
    asm volatile("s_waitcnt lgkmcnt(0)" ::: "memory"); __builtin_amdgcn_sched_barrier(0); \
    __builtin_amdgcn_s_setprio(1)
#define PH_END() __builtin_amdgcn_s_setprio(0); __builtin_amdgcn_sched_barrier(0); \
    __builtin_amdgcn_s_barrier(); __builtin_amdgcn_sched_barrier(0)
#define PH_END_VM(n) __builtin_amdgcn_s_setprio(0); __builtin_amdgcn_sched_barrier(0); \
    asm volatile("s_waitcnt vmcnt(" #n ")" ::: "memory"); \
    __builtin_amdgcn_s_barrier(); __builtin_amdgcn_sched_barrier(0)

// ---------------- GEMM1 (8-phase, persistent): H = relu(gather(hbf) @ wiT^T) ----------------
__global__ __launch_bounds__(512, 1) void gemm1_8p(
    const u16* __restrict__ hbf, const u16* __restrict__ wiT, size_t wstride,
    const int* __restrict__ slot_token, const int* __restrict__ counts,
    const u16* __restrict__ zerobuf, u16* __restrict__ Hbuf,
    int p0, int nItems, const int* __restrict__ glist, const int* __restrict__ ngp,
    const int* __restrict__ gslot)
{
    constexpr int KDIM = kD, NTn = kF / 256, NKT = KDIM / 64, NI = NKT / 2;
    int tid = threadIdx.x, w = tid >> 6, l = tid & 63;
    int wr = w >> 2, wc = w & 3;
    int fr = l & 15, fq = l >> 4;
    int r0 = w * 32 + (l >> 2), r1 = r0 + 16;
    int clog = (l & 3) ^ ((l >> 3) & 3);
    int sw = (fr >> 1) & 3;

    extern __shared__ __align__(16) u16 lds[];
    u16* Ap = lds;
    u16* Bp = lds + 32768;
    int* slots = (int*)(lds + 65536);
    u16* dA = Ap + w * 1024;
    u16* dB = Bp + w * 1024;
    const u16* rA = Ap + (wr * 128 + fr) * 32 + ((fq ^ sw) << 3);
    const u16* rB = Bp + (wc * 64 + fr) * 32 + ((fq ^ sw) << 3);
    int nblk = gridDim.x;
    int xcd = blockIdx.x & 7, idx32 = blockIdx.x >> 3;
    int nlocal = 0;
    if (glist) {
        int ng = *ngp;
        int nTx = (xcd < ng) ? (((ng - 1 - xcd) >> 3) + 1) : 0;
        nlocal = nTx * NTn;
    }

    #pragma unroll 1
    for (int it = 0; ; ++it) {
        int e, nt;
        size_t hrow0;
        if (glist) {
            int q = idx32 + 32 * it;
            if (q >= nlocal) break;
            int lt = q / NTn;
            nt = q % NTn;
            int gpk = glist[xcd + 8 * lt];
            e = gpk >> 8;
            int t = gpk & 255;
            int rowbase = e * (kB * kC) + t * 256;
            hrow0 = (size_t)rowbase;
            if (tid < 256) slots[tid] = gslot[rowbase + tid];
        } else {
            int i = blockIdx.x + it * nblk;
            if (i >= nItems) break;
            nt = i % NTn;
            int g = i / NTn;
            int mt = g & 1, pem = p0 + (g >> 1);
            e = pem >> 3;
            int b = pem & 7;
            int pair = b * kE + e;
            int cnt = counts[pair];
            if (mt * 256 >= cnt) continue;
            hrow0 = (size_t)(pem - p0) * kC + mt * 256;
            if (tid < 256) {
                int s = slot_token[pair * kC + mt * 256 + tid];
                slots[tid] = (s >= 0) ? ((b << 11) | s) : -1;
            }
        }
        __syncthreads();

        int sl0 = slots[r0], sl1 = slots[r1];
        const u16* sA0 = (sl0 >= 0) ? hbf + (size_t)sl0 * kD + clog * 8 : zerobuf + clog * 8;
        const u16* sA1 = (sl1 >= 0) ? hbf + (size_t)sl1 * kD + clog * 8 : zerobuf + clog * 8;
        const u16* wbase = wiT + (size_t)e * wstride;
        const u16* sB0 = wbase + (size_t)(nt * 256 + r0) * KDIM + clog * 8;
        const u16* sB1 = wbase + (size_t)(nt * 256 + r1) * KDIM + clog * 8;

        f32x4 acc[8][4];
        #pragma unroll
        for (int m = 0; m < 8; m++)
            #pragma unroll
            for (int n = 0; n < 4; n++) acc[m][n] = (f32x4){0.f, 0.f, 0.f, 0.f};
        bf16x8 af[8], bfr[4];

        SA8(0, 0) SB8(0, 0) SA8(0, 1) SB8(0, 1) SA8(1, 0) SB8(1, 0) SA8(1, 1)
        asm volatile("s_waitcnt vmcnt(6)" ::: "memory");
        __builtin_amdgcn_s_barrier();
        __builtin_amdgcn_sched_barrier(0);

        #pragma unroll 1
        for (int i2 = 0; i2 < NI - 1; ++i2) {
            int kt0 = 2 * i2;
            RDA03(0, 0) SB8(kt0 + 1, 1) PH_MID(); MM8(0) PH_END();
            RDA47(0, 0) SA8(kt0 + 2, 0) PH_MID(); MM8(4) PH_END();
            RDA03(0, 1) SB8(kt0 + 2, 0) PH_MID(); MM8(0) PH_END();
            RDA47(0, 1) SA8(kt0 + 2, 1) PH_MID(); MM8(4) PH_END_VM(6);
            RDA03(1, 0) SB8(kt0 + 2, 1) PH_MID(); MM8(0) PH_END();
            RDA47(1, 0) SA8(kt0 + 3, 0) PH_MID(); MM8(4) PH_END();
            RDA03(1, 1) SB8(kt0 + 3, 0) PH_MID(); MM8(0) PH_END();
            RDA47(1, 1) SA8(kt0 + 3, 1) PH_MID(); MM8(4) PH_END_VM(6);
        }
        RDA03(0, 0) SB8(NKT - 1, 1) PH_MID(); MM8(0) PH_END();
        RDA47(0, 0) PH_MID(); MM8(4) PH_END();
        RDA03(0, 1) PH_MID(); MM8(0) PH_END();
        RDA47(0, 1) PH_MID(); MM8(4) PH_END_VM(0);
        RDA03(1, 0) PH_MID(); MM8(0) PH_END();
        RDA47(1, 0) PH_MID(); MM8(4) PH_END();
        RDA03(1, 1) PH_MID(); MM8(0) PH_END();
        RDA47(1, 1) PH_MID(); MM8(4) __builtin_amdgcn_s_setprio(0); __builtin_amdgcn_sched_barrier(0);

        int c0 = nt * 256 + wc * 64;
        #pragma unroll
        for (int m = 0; m < 8; m++) {
            #pragma unroll
            for (int j = 0; j < 4; j++) {
                int row = wr * 128 + m * 16 + fq * 4 + j;
                size_t rb = (hrow0 + row) * kF;
                #pragma unroll
                for (int n = 0; n < 4; n++)
                    Hbuf[rb + c0 + n * 16 + fr] = f2bf(fmaxf(acc[m][n][j], 0.f));
            }
        }
        __syncthreads();   // protect slots[] before next item
    }
}

// ---------------- GEMM2 (8-phase, persistent): out = (H @ woT^T) * max_prob ----------------
__global__ __launch_bounds__(512, 1) void gemm2_8p(
    const u16* __restrict__ Hbuf, const u16* __restrict__ woT, size_t wstride,
    const int* __restrict__ slot_token, const int* __restrict__ counts,
    const float* __restrict__ maxprob, float* __restrict__ outp,
    int p0, int nItems, const int* __restrict__ glist, const int* __restrict__ ngp,
    const int* __restrict__ gslot)
{
    constexpr int KDIM = kF, NTn = kD / 256, NKT = KDIM / 64, NI = NKT / 2;
    int tid = threadIdx.x, w = tid >> 6, l = tid & 63;
    int wr = w >> 2, wc = w & 3;
    int fr = l & 15, fq = l >> 4;
    int r0 = w * 32 + (l >> 2), r1 = r0 + 16;
    int clog = (l & 3) ^ ((l >> 3) & 3);
    int sw = (fr >> 1) & 3;

    extern __shared__ __align__(16) u16 lds[];
    u16* Ap = lds;
    u16* Bp = lds + 32768;
    int* slots = (int*)(lds + 65536);
    u16* dA = Ap + w * 1024;
    u16* dB = Bp + w * 1024;
    const u16* rA = Ap + (wr * 128 + fr) * 32 + ((fq ^ sw) << 3);
    const u16* rB = Bp + (wc * 64 + fr) * 32 + ((fq ^ sw) << 3);
    int nblk = gridDim.x;
    int xcd = blockIdx.x & 7, idx32 = blockIdx.x >> 3;
    int nlocal = 0;
    if (glist) {
        int ng = *ngp;
        int nTx = (xcd < ng) ? (((ng - 1 - xcd) >> 3) + 1) : 0;
        nlocal = nTx * NTn;
    }

    #pragma unroll 1
    for (int it = 0; ; ++it) {
        int e, nt;
        size_t hrow0;
        if (glist) {
            int q = idx32 + 32 * it;
            if (q >= nlocal) break;
            int lt = q / NTn;
            nt = q % NTn;
            int gpk = glist[xcd + 8 * lt];
            e = gpk >> 8;
            int t = gpk & 255;
            int rowbase = e * (kB * kC) + t * 256;
            hrow0 = (size_t)rowbase;
            if (tid < 256) slots[tid] = gslot[rowbase + tid];
        } else {
            int i = blockIdx.x + it * nblk;
            if (i >= nItems) break;
            nt = i % NTn;
            int g = i / NTn;
            int mt = g & 1, pem = p0 + (g >> 1);
            e = pem >> 3;
            int b = pem & 7;
            int pair = b * kE + e;
            int cnt = counts[pair];
            if (mt * 256 >= cnt) continue;
            hrow0 = (size_t)(pem - p0) * kC + mt * 256;
            if (tid < 256) {
                int s = slot_token[pair * kC + mt * 256 + tid];
                slots[tid] = (s >= 0) ? ((b << 11) | s) : -1;
            }
        }
        __syncthreads();

        const u16* sA0 = Hbuf + (hrow0 + r0) * kF + clog * 8;
        const u16* sA1 = Hbuf + (hrow0 + r1) * kF + clog * 8;
        const u16* wbase = woT + (size_t)e * wstride;
        const u16* sB0 = wbase + (size_t)(nt * 256 + r0) * KDIM + clog * 8;
        const u16* sB1 = wbase + (size_t)(nt * 256 + r1) * KDIM + clog * 8;

        f32x4 acc[8][4];
        #pragma unroll
        for (int m = 0; m < 8; m++)
            #pragma unroll
            for (int n = 0; n < 4; n++) acc[m][n] = (f32x4){0.f, 0.f, 0.f, 0.f};
        bf16x8 af[8], bfr[4];

        SA8(0, 0) SB8(0, 0) SA8(0, 1) SB8(0, 1) SA8(1, 0) SB8(1, 0) SA8(1, 1)
        asm volatile("s_waitcnt vmcnt(6)" ::: "memory");
        __builtin_amdgcn_s_barrier();
        __builtin_amdgcn_sched_barrier(0);

        #pragma unroll 1
        for (int i2 = 0; i2 < NI - 1; ++i2) {
            int kt0 = 2 * i2;
            RDA03(0, 0) SB8(kt0 + 1, 1) PH_MID(); MM8(0) PH_END();
            RDA47(0, 0) SA8(kt0 + 2, 0) PH_MID(); MM8(4) PH_END();
            RDA03(0, 1) SB8(kt0 + 2, 0) PH_MID(); MM8(0) PH_END();
            RDA47(0, 1) SA8(kt0 + 2, 1) PH_MID(); MM8(4) PH_END_VM(6);
            RDA03(1, 0) SB8(kt0 + 2, 1) PH_MID(); MM8(0) PH_END();
            RDA47(1, 0) SA8(kt0 + 3, 0) PH_MID(); MM8(4) PH_END();
            RDA03(1, 1) SB8(kt0 + 3, 0) PH_MID(); MM8(0) PH_END();
            RDA47(1, 1) SA8(kt0 + 3, 1) PH_MID(); MM8(4) PH_END_VM(6);
        }
        RDA03(0, 0) SB8(NKT - 1, 1) PH_MID(); MM8(0) PH_END();
        RDA47(0, 0) PH_MID(); MM8(4) PH_END();
        RDA03(0, 1) PH_MID(); MM8(0) PH_END();
        RDA47(0, 1) PH_MID(); MM8(4) PH_END_VM(0);
        RDA03(1, 0) PH_MID(); MM8(0) PH_END();
        RDA47(1, 0) PH_MID(); MM8(4) PH_END();
        RDA03(1, 1) PH_MID(); MM8(0) PH_END();
        RDA47(1, 1) PH_MID(); MM8(4) __builtin_amdgcn_s_setprio(0); __builtin_amdgcn_sched_barrier(0);

        int c0 = nt * 256 + wc * 64;
        #pragma unroll
        for (int m = 0; m < 8; m++) {
            #pragma unroll
            for (int j = 0; j < 4; j++) {
                int rl = wr * 128 + m * 16 + fq * 4 + j;
                int gs = slots[rl];
                if (gs >= 0) {
                    float p = maxprob[gs];
                    size_t ob = (size_t)gs * kD;
                    #pragma unroll
                    for (int n = 0; n < 4; n++)
                        outp[ob + c0 + n * 16 + fr] = acc[m][n][j] * p;
                }
            }
        }
        __syncthreads();   // protect slots[] before next item
    }
}

#undef SA8
#undef SB8
#undef RDA03
#undef RDA47
#undef MM8
#undef PH_MID
#undef PH_END
#undef PH_END_VM

// ---------------- naive fp32 fallback (proven) ----------------
__global__ __launch_bounds__(256) void ngemm1_k(
    const float* __restrict__ hidden, const float* __restrict__ wi,
    const int* __restrict__ slot_token, const int* __restrict__ counts,
    float* __restrict__ H, int pair)
{
    int b = pair >> 3, e = pair & 7;
    int cnt = counts[pair];
    int c0 = blockIdx.y * 64, f0 = blockIdx.x * 64;
    if (c0 >= cnt) return;
    __shared__ float As[64][17];
    __shared__ float Bs[16][65];
    __shared__ int slots[64];
    int tx = threadIdx.x, ty = threadIdx.y;
    int tid = ty * 16 + tx;
    if (tid < 64) slots[tid] = slot_token[pair * kC + c0 + tid];
    __syncthreads();
    float acc[4][4];
    #pragma unroll
    for (int i = 0; i < 4; i++)
        #pragma unroll
        for (int j = 0; j < 4; j++) acc[i][j] = 0.f;
    int ar = tid >> 2, ak = (tid & 3) * 4;
    int bd = tid >> 4, bf = (tid & 15) * 4;
    const float* wie = wi + (size_t)e * kD * kF;
    for (int k0 = 0; k0 < kD; k0 += 16) {
        int sl = slots[ar];
        if (sl >= 0) {
            float4 v = *(const float4*)(hidden + (size_t)(b * kS + sl) * kD + k0 + ak);
            As[ar][ak] = v.x; As[ar][ak + 1] = v.y; As[ar][ak + 2] = v.z; As[ar][ak + 3] = v.w;
        } else {
            As[ar][ak] = 0.f; As[ar][ak + 1] = 0.f; As[ar][ak + 2] = 0.f; As[ar][ak + 3] = 0.f;
        }
        float4 wv = *(const float4*)(wie + (size_t)(k0 + bd) * kF + f0 + bf);
        Bs[bd][bf] = wv.x; Bs[bd][bf + 1] = wv.y; Bs[bd][bf + 2] = wv.z; Bs[bd][bf + 3] = wv.w;
        __syncthreads();
        #pragma unroll
        for (int kk = 0; kk < 16; kk++) {
            float a[4], bv[4];
            #pragma unroll
            for (int i = 0; i < 4; i++) a[i] = As[ty * 4 + i][kk];
            #pragma unroll
            for (int j = 0; j < 4; j++) bv[j] = Bs[kk][tx * 4 + j];
            #pragma unroll
            for (int i = 0; i < 4; i++)
                #pragma unroll
                for (int j = 0; j < 4; j++) acc[i][j] += a[i] * bv[j];
        }
        __syncthreads();
    }
    #pragma unroll
    for (int i = 0; i < 4; i++) {
        int row = c0 + ty * 4 + i;
        #pragma unroll
        for (int j = 0; j < 4; j++)
            H[(size_t)row * kF + f0 + tx * 4 + j] = fmaxf(acc[i][j], 0.f);
    }
}

__global__ __launch_bounds__(256) void ngemm2_k(
    const float* __restrict__ H, const float* __restrict__ wo,
    const int* __restrict__ slot_token, const int* __restrict__ counts,
    const float* __restrict__ maxprob, float* __restrict__ outp, int pair)
{
    int b = pair >> 3, e = pair & 7;
    int cnt = counts[pair];
    int c0 = blockIdx.y * 64, d0 = blockIdx.x * 64;
    if (c0 >= cnt) return;
    __shared__ float As[64][17];
    __shared__ float Bs[16][65];
    __shared__ int slots[64];
    int tx = threadIdx.x, ty = threadIdx.y;
    int tid = ty * 16 + tx;
    if (tid < 64) slots[tid] = slot_token[pair * kC + c0 + tid];
    __syncthreads();
    float acc[4][4];
    #pragma unroll
    for (int i = 0; i < 4; i++)
        #pragma unroll
        for (int j = 0; j < 4; j++) acc[i][j] = 0.f;
    int ar = tid >> 2, ak = (tid & 3) * 4;
    int bd = tid >> 4, bf = (tid & 15) * 4;
    const float* woe = wo + (size_t)e * kF * kD;
    for (int k0 = 0; k0 < kF; k0 += 16) {
        float4 v = *(const float4*)(H + (size_t)(c0 + ar) * kF + k0 + ak);
        As[ar][ak] = v.x; As[ar][ak + 1] = v.y; As[ar][ak + 2] = v.z; As[ar][ak + 3] = v.w;
        float4 wv = *(const float4*)(woe + (size_t)(k0 + bd) * kD + d0 + bf);
        Bs[bd][bf] = wv.x; Bs[bd][bf + 1] = wv.y; Bs[bd][bf + 2] = wv.z; Bs[bd][bf + 3] = wv.w;
        __syncthreads();
        #pragma unroll
        for (int kk = 0; kk < 16; kk++) {
            float a[4], bv[4];
            #pragma unroll
            for (int i = 0; i < 4; i++) a[i] = As[ty * 4 + i][kk];
            #pragma unroll
            for (int j = 0; j < 4; j++) bv[j] = Bs[kk][tx * 4 + j];
            #pragma unroll
            for (int i = 0; i < 4; i++)
                #pragma unroll
                for (int j = 0; j < 4; j++) acc[i][j] += a[i] * bv[j];
        }
        __syncthreads();
    }
    #pragma unroll
    for (int i = 0; i < 4; i++) {
        int s = slots[ty * 4 + i];
        if (s >= 0) {
            float p = maxprob[b * kS + s];
            size_t ob = (size_t)(b * kS + s) * kD;
            #pragma unroll
            for (int j = 0; j < 4; j++)
                outp[ob + d0 + tx * 4 + j] = acc[i][j] * p;
        }
    }
}

extern "C" void kernel_launch(void* const* d_in, const int* in_sizes, int n_in,
                              void* d_out, int out_size, void* d_ws, size_t ws_size,
                              hipStream_t stream)
{
    const float* hidden = (const float*)d_in[0];
    const float* rw     = (const float*)d_in[1];
    const float* wi     = (const float*)d_in[2];
    const float* wo     = (const float*)d_in[3];
    float* outp   = (float*)d_out;
    float* logits = outp + (size_t)kB * kS * kD;
    float* expidx = logits + (size_t)kB * kS * kE;

    char* ws = (char*)d_ws;
    size_t off = 0;
    auto alloc = [&](size_t bytes) -> char* {
        char* p = ws + off; off += (bytes + 255) & ~(size_t)255; return p;
    };
    int*   slot_token = (int*)  alloc((size_t)kB * kE * kC * 4);
    int*   counts     = (int*)  alloc((size_t)kB * kE * 4);
    int*   expert_id  = (int*)  alloc((size_t)kB * kS * 4);
    float* maxprob    = (float*)alloc((size_t)kB * kS * 4);
    int*   gslot      = (int*)  alloc((size_t)kE * kB * kC * 4);
    int*   glist      = (int*)  alloc(256 * 4);
    int*   ngp        = (int*)  alloc(256);
    int*   droplist   = (int*)  alloc((size_t)kB * kS * 4);
    int*   ndropp     = (int*)  alloc(256);
    size_t small_off = off;

    const size_t wsz   = (size_t)kD * kF * 2;
    const size_t hsz   = (size_t)kC * kF * 2;
    const size_t hbfsz = (size_t)kB * kS * kD * 2;

    hipFuncSetAttribute(reinterpret_cast<const void*>(gemm1_8p),
                        hipFuncAttributeMaxDynamicSharedMemorySize, kSmemBytes);
    hipFuncSetAttribute(reinterpret_cast<const void*>(gemm2_8p),
                        hipFuncAttributeMaxDynamicSharedMemorySize, kSmemBytes);

    bool tierA = ws_size >= small_off + 2 * kE * wsz + hbfsz + 4096 + 4 * hsz;
    bool tierB = !tierA && ws_size >= small_off + 2 * wsz + hbfsz + 4096 + hsz;

    if (tierA) {
        u16* wiT = (u16*)alloc(kE * wsz);
        u16* woT = (u16*)alloc(kE * wsz);
        u16* hbf = (u16*)alloc(hbfsz);
        u16* zerobuf = (u16*)alloc(4096);
        int Gb = (int)((ws_size - off) / hsz);
        if (Gb > kB * kE) Gb = kB * kE;
        if (Gb < 1) Gb = 1;
        u16* Hbuf = (u16*)alloc((size_t)Gb * hsz);

        init_k<<<1, 256, 0, stream>>>((uint4*)outp, (uint4*)zerobuf, ndropp, 0);
        router_k<<<kB * kS / 4, 256, 0, stream>>>(hidden, rw, logits, expert_id, maxprob, hbf);
        scan_k<<<kB, 64, 0, stream>>>(expert_id, slot_token, counts, expidx, droplist, ndropp);
        build_k<<<1, 256, 0, stream>>>(counts, slot_token, gslot, glist, ngp);
        zdrop_k<<<512, 256, 0, stream>>>(droplist, ndropp, (float4*)outp);
        transpose_v<<<dim3(kF / 64, kD / 64, kE), 256, 0, stream>>>(wi, wiT, kD, kF);
        transpose_v<<<dim3(kD / 64, kF / 64, kE), 256, 0, stream>>>(wo, woT, kF, kD);

        if (Gb == kB * kE) {
            gemm1_8p<<<256, 512, kSmemBytes, stream>>>(
                hbf, wiT, (size_t)kD * kF, slot_token, counts, zerobuf, Hbuf,
                0, 0, glist, ngp, gslot);
            gemm2_8p<<<256, 512, kSmemBytes, stream>>>(
                Hbuf, woT, (size_t)kD * kF, slot_token, counts, maxprob, outp,
                0, 0, glist, ngp, gslot);
        } else {
            for (int p0 = 0; p0 < kB * kE; p0 += Gb) {
                int g = kB * kE - p0 < Gb ? kB * kE - p0 : Gb;
                gemm1_8p<<<g * 2 * (kF / 256), 512, kSmemBytes, stream>>>(
                    hbf, wiT, (size_t)kD * kF, slot_token, counts, zerobuf, Hbuf,
                    p0, g * 2 * (kF / 256), nullptr, nullptr, nullptr);
                gemm2_8p<<<g * 2 * (kD / 256), 512, kSmemBytes, stream>>>(
                    Hbuf, woT, (size_t)kD * kF, slot_token, counts, maxprob, outp,
                    p0, g * 2 * (kD / 256), nullptr, nullptr, nullptr);
            }
        }
    } else if (tierB) {
        u16* wiT = (u16*)alloc(wsz);
        u16* woT = (u16*)alloc(wsz);
        u16* hbf = (u16*)alloc(hbfsz);
        u16* zerobuf = (u16*)alloc(4096);
        int Gb = (int)((ws_size - off) / hsz);
        if (Gb > kB) Gb = kB;
        if (Gb < 1) Gb = 1;
        u16* Hbuf = (u16*)alloc((size_t)Gb * hsz);

        init_k<<<2048, 256, 0, stream>>>((uint4*)outp, (uint4*)zerobuf, ndropp, 1);
        router_k<<<kB * kS / 4, 256, 0, stream>>>(hidden, rw, logits, expert_id, maxprob, hbf);
        scan_k<<<kB, 64, 0, stream>>>(expert_id, slot_token, counts, expidx, nullptr, nullptr);
        for (int e = 0; e < kE; e++) {
            transpose_v<<<dim3(kF / 64, kD / 64, 1), 256, 0, stream>>>(
                wi + (size_t)e * kD * kF, wiT, kD, kF);
            transpose_v<<<dim3(kD / 64, kF / 64, 1), 256, 0, stream>>>(
                wo + (size_t)e * kD * kF, woT, kF, kD);
            for (int b0 = 0; b0 < kB; b0 += Gb) {
                int g = kB - b0 < Gb ? kB - b0 : Gb;
                int p0 = e * 8 + b0;
                gemm1_8p<<<g * 2 * (kF / 256), 512, kSmemBytes, stream>>>(
                    hbf, wiT, 0, slot_token, counts, zerobuf, Hbuf,
                    p0, g * 2 * (kF / 256), nullptr, nullptr, nullptr);
                gemm2_8p<<<g * 2 * (kD / 256), 512, kSmemBytes, stream>>>(
                    Hbuf, woT, 0, slot_token, counts, maxprob, outp,
                    p0, g * 2 * (kD / 256), nullptr, nullptr, nullptr);
            }
        }
    } else {
        float* H = (float*)alloc((size_t)kC * kF * 4);
        init_k<<<2048, 256, 0, stream>>>((uint4*)outp, nullptr, ndropp, 1);
        router_k<<<kB * kS / 4, 256, 0, stream>>>(hidden, rw, logits, expert_id, maxprob, nullptr);
        scan_k<<<kB, 64, 0, stream>>>(expert_id, slot_token, counts, expidx, nullptr, nullptr);
        for (int pair = 0; pair < kB * kE; pair++) {
            ngemm1_k<<<dim3(kF / 64, kC / 64), dim3(16, 16), 0, stream>>>(
                hidden, wi, slot_token, counts, H, pair);
            ngemm2_k<<<dim3(kD / 64, kC / 64), dim3(16, 16), 0, stream>>>(
                H, wo, slot_token, counts, maxprob, outp, pair);
        }
    }
}

// Round 20
// 810.043 us; speedup vs baseline: 1.0298x; 1.0298x over previous
//
#include <hip/hip_runtime.h>
#include <stdint.h>

static constexpr int kB = 8, kS = 2048, kD = 1024, kF = 4096, kE = 8, kC = 512;
static constexpr int kMaxTiles = 72;   // sum_e ceil(tot_e/256) <= 16384/256 + 8

typedef unsigned short u16;
typedef __attribute__((ext_vector_type(8))) short bf16x8;
typedef __attribute__((ext_vector_type(4))) float f32x4;

__device__ __forceinline__ float bf2f(u16 u) {
    union { uint32_t u; float f; } v; v.u = ((uint32_t)u) << 16; return v.f;
}
__device__ __forceinline__ u16 f2bf(float f) {
    union { float f; uint32_t u; } v; v.f = f;
    return (u16)((v.u + 0x7fffu + ((v.u >> 16) & 1u)) >> 16);
}
__device__ __forceinline__ void gload16(const u16* g, u16* l) {
    __builtin_amdgcn_global_load_lds(
        (__attribute__((address_space(1))) void*)(u16*)g,
        (__attribute__((address_space(3))) void*)l, 16, 0, 0);
}

static constexpr int kSmemBytes = 132096;  // A 64KB + B 64KB + slots 1KB

// ---------------- init: zero page, reset ndrop (+ full out sweep for fallback tiers) --------
__global__ void init_k(uint4* __restrict__ outz, uint4* __restrict__ zb,
                       int* __restrict__ ndropp, int sweep) {
    if (blockIdx.x == 0 && threadIdx.x == 0 && ndropp) *ndropp = 0;
    if (blockIdx.x == 0 && zb && threadIdx.x < 256) zb[threadIdx.x] = (uint4){0, 0, 0, 0};
    if (!sweep) return;
    const size_t n = (size_t)kB * kS * kD * 4 / 16;
    size_t stride = (size_t)gridDim.x * blockDim.x;
    for (size_t i = (size_t)blockIdx.x * blockDim.x + threadIdx.x; i < n; i += stride)
        outz[i] = (uint4){0, 0, 0, 0};
}

// ---------------- zero only dropped-token rows of out ----------------
__global__ void zdrop_k(const int* __restrict__ droplist, const int* __restrict__ ndropp,
                        float4* __restrict__ outp) {
    int nd = *ndropp;
    size_t total = (size_t)nd * (kD / 4);
    size_t stride = (size_t)gridDim.x * blockDim.x;
    for (size_t i = (size_t)blockIdx.x * blockDim.x + threadIdx.x; i < total; i += stride) {
        int row = droplist[i >> 8];
        int col = (int)(i & 255);
        outp[(size_t)row * 256 + col] = (float4){0.f, 0.f, 0.f, 0.f};
    }
}

// ---------------- router (fused): fp32 logits + argmax + writes bf16 hidden image ----------
__global__ __launch_bounds__(256) void router_k(
    const float* __restrict__ hidden, const float* __restrict__ rw,
    float* __restrict__ logits_out, int* __restrict__ expert_id, float* __restrict__ maxprob,
    u16* __restrict__ hbf)
{
    int token = blockIdx.x * 4 + (threadIdx.x >> 6);
    int lane = threadIdx.x & 63;
    const float* hrow = hidden + (size_t)token * kD;
    float acc[8] = {0, 0, 0, 0, 0, 0, 0, 0};
    for (int d0 = lane * 4; d0 < kD; d0 += 256) {
        float4 h4 = *(const float4*)(hrow + d0);
        float hv[4] = {h4.x, h4.y, h4.z, h4.w};
        if (hbf) {
            u16 t4[4] = {f2bf(h4.x), f2bf(h4.y), f2bf(h4.z), f2bf(h4.w)};
            *(uint2*)(hbf + (size_t)token * kD + d0) = *(const uint2*)t4;
        }
        #pragma unroll
        for (int j = 0; j < 4; j++) {
            const float* wr = rw + (size_t)(d0 + j) * 8;
            float4 w0 = *(const float4*)wr, w1 = *(const float4*)(wr + 4);
            acc[0] += hv[j] * w0.x; acc[1] += hv[j] * w0.y;
            acc[2] += hv[j] * w0.z; acc[3] += hv[j] * w0.w;
            acc[4] += hv[j] * w1.x; acc[5] += hv[j] * w1.y;
            acc[6] += hv[j] * w1.z; acc[7] += hv[j] * w1.w;
        }
    }
    #pragma unroll
    for (int off = 32; off >= 1; off >>= 1) {
        #pragma unroll
        for (int e = 0; e < 8; e++) acc[e] += __shfl_down(acc[e], off, 64);
    }
    if (lane == 0) {
        float m = acc[0];
        #pragma unroll
        for (int e = 1; e < 8; e++) m = fmaxf(m, acc[e]);
        float ex[8], s = 0.f;
        #pragma unroll
        for (int e = 0; e < 8; e++) { ex[e] = expf(acc[e] - m); s += ex[e]; }
        int best = 0; float bv = -1.f;
        #pragma unroll
        for (int e = 0; e < 8; e++) {
            float p = ex[e] / s;
            if (p > bv) { bv = p; best = e; }
            logits_out[(size_t)token * 8 + e] = acc[e];
        }
        expert_id[token] = best;
        maxprob[token] = bv;
    }
}

// ---------------- capacity scan (+ dropped-token list) ----------------
__global__ __launch_bounds__(64) void scan_k(
    const int* __restrict__ expert_id, int* __restrict__ slot_token,
    int* __restrict__ counts, float* __restrict__ expidx_out,
    int* __restrict__ droplist, int* __restrict__ ndropp)
{
    __shared__ int eids[kS];
    int b = blockIdx.x, tid = threadIdx.x;
    for (int s = tid; s < kS; s += 64) eids[s] = expert_id[b * kS + s];
    __syncthreads();
    if (tid < kE) {
        int e = tid, cnt = 0;
        for (int s = 0; s < kS; s++) {
            if (eids[s] == e) {
                if (cnt < kC) {
                    slot_token[(b * kE + e) * kC + cnt] = s;
                    expidx_out[b * kS + s] = (float)e;
                    cnt++;
                } else {
                    expidx_out[b * kS + s] = 0.f;
                    if (droplist) {
                        int di = atomicAdd(ndropp, 1);
                        droplist[di] = (b << 11) | s;
                    }
                }
            }
        }
        counts[b * kE + e] = cnt;
        for (int c = cnt; c < kC; c++) slot_token[(b * kE + e) * kC + c] = -1;
    }
}

// ---------------- build: pack experts across batches; gslot[e][i] = b*2048+s (-1 pad) ------
__global__ __launch_bounds__(256) void build_k(
    const int* __restrict__ counts, const int* __restrict__ slot_token,
    int* __restrict__ gslot, int* __restrict__ glist, int* __restrict__ ngp)
{
    __shared__ int offs[kE][kB];
    __shared__ int tiles[kE];
    int tid = threadIdx.x;
    if (tid < kE) {
        int e = tid, o = 0;
        #pragma unroll
        for (int b = 0; b < kB; b++) { offs[e][b] = o; o += counts[b * kE + e]; }
        tiles[e] = (o + 255) >> 8;
    }
    __syncthreads();
    for (int e = 0; e < kE; e++) {
        int padded = tiles[e] << 8;
        for (int i = tid; i < padded; i += 256) gslot[e * (kB * kC) + i] = -1;
    }
    __syncthreads();
    for (int e = 0; e < kE; e++)
        for (int b = 0; b < kB; b++) {
            int cnt = counts[b * kE + e], base = offs[e][b];
            for (int c = tid; c < cnt; c += 256)
                gslot[e * (kB * kC) + base + c] = (b << 11) | slot_token[(b * kE + e) * kC + c];
        }
    if (tid == 0) {
        int n = 0;
        for (int e = 0; e < kE; e++)
            for (int t = 0; t < tiles[e]; t++) glist[n++] = (e << 8) | t;
        *ngp = n;
    }
}

// ---------------- vectorized convert-transpose: fp32 [R][Cn] -> bf16 [Cn][R] ----------------
__global__ __launch_bounds__(256) void transpose_v(
    const float* __restrict__ src, u16* __restrict__ dst, int R, int Cn)
{
    __shared__ u16 tl[64][68];
    size_t eo = (size_t)blockIdx.z * R * Cn;
    int c0 = blockIdx.x * 64, r0 = blockIdx.y * 64;
    int t = threadIdx.x;
    int tx = t & 15, ty = t >> 4;
    #pragma unroll
    for (int i = 0; i < 4; i++) {
        int r = ty + 16 * i;
        float4 v = *(const float4*)(src + eo + (size_t)(r0 + r) * Cn + c0 + tx * 4);
        tl[tx * 4 + 0][r] = f2bf(v.x);
        tl[tx * 4 + 1][r] = f2bf(v.y);
        tl[tx * 4 + 2][r] = f2bf(v.z);
        tl[tx * 4 + 3][r] = f2bf(v.w);
    }
    __syncthreads();
    int seg = t & 7, clb = t >> 3;
    #pragma unroll
    for (int ii = 0; ii < 2; ii++) {
        int cl = clb + 32 * ii;
        uint4 v = *(const uint4*)&tl[cl][seg * 8];
        *(uint4*)(dst + eo + (size_t)(c0 + cl) * R + r0 + seg * 8) = v;
    }
}

// ================= shared 8-phase machinery (round-12-proven) =================
#define SA8(kt, kh) { int off_ = (((kt) & 1) << 14) + ((kh) << 13); int go_ = (kt) * 64 + (kh) * 32; \
    gload16(sA0 + go_, dA + off_); gload16(sA1 + go_, dA + off_ + 512); }
#define SB8(kt, kh) { int off_ = (((kt) & 1) << 14) + ((kh) << 13); int go_ = (kt) * 64 + (kh) * 32; \
    gload16(sB0 + go_, dB + off_); gload16(sB1 + go_, dB + off_ + 512); }
#define RDA03(buf, kh) { const u16* a_ = rA + ((buf) << 14) + ((kh) << 13); \
    const u16* b_ = rB + ((buf) << 14) + ((kh) << 13); \
    _Pragma("unroll") for (int m_ = 0; m_ < 4; m_++) af[m_] = *(const bf16x8*)(a_ + m_ * 512); \
    _Pragma("unroll") for (int n_ = 0; n_ < 4; n_++) bfr[n_] = *(const bf16x8*)(b_ + n_ * 512); }
#define RDA47(buf, kh) { const u16* a_ = rA + ((buf) << 14) + ((kh) << 13); \
    _Pragma("unroll") for (int m_ = 4; m_ < 8; m_++) af[m_] = *(const bf16x8*)(a_ + m_ * 512); }
#define MM8(mlo) { _Pragma("unroll") for (int m_ = 0; m_ < 4; m_++) \
    { _Pragma("unroll") for (int n_ = 0; n_ < 4; n_++) \
      acc[(mlo) + m_][n_] = __builtin_amdgcn_mfma_f32_16x16x32_bf16(af[(mlo) + m_], bfr[n_], acc[(mlo) + m_][n_], 0, 0, 0); } }
#define PH_MID() __builtin_amdgcn_sched_barrier(0); __builtin_amdgcn_s_barrier(); \
    asm volatile("s_waitcnt lgkmcnt(0)" ::: "memory"); __builtin_amdgcn_sched_barrier(0); \
    __builtin_amdgcn_s_setprio(1)
#define PH_END() __builtin_amdgcn_s_setprio(0); __builtin_amdgcn_sched_barrier(0); \
    __builtin_amdgcn_s_barrier(); __builtin_amdgcn_sched_barrier(0)
#define PH_END_VM(n) __builtin_amdgcn_s_setprio(0); __builtin_amdgcn_sched_barrier(0); \
    asm volatile("s_waitcnt vmcnt(" #n ")" ::: "memory"); \
    __builtin_amdgcn_s_barrier(); __builtin_amdgcn_sched_barrier(0)

#define KLOOP(NKTc, NIc) \
    SA8(0, 0) SB8(0, 0) SA8(0, 1) SB8(0, 1) SA8(1, 0) SB8(1, 0) SA8(1, 1) \
    asm volatile("s_waitcnt vmcnt(6)" ::: "memory"); \
    __builtin_amdgcn_s_barrier(); \
    __builtin_amdgcn_sched_barrier(0); \
    _Pragma("unroll 1") \
    for (int i2 = 0; i2 < (NIc) - 1; ++i2) { \
        int kt0 = 2 * i2; \
        RDA03(0, 0) SB8(kt0 + 1, 1) PH_MID(); MM8(0) PH_END(); \
        RDA47(0, 0) SA8(kt0 + 2, 0) PH_MID(); MM8(4) PH_END(); \
        RDA03(0, 1) SB8(kt0 + 2, 0) PH_MID(); MM8(0) PH_END(); \
        RDA47(0, 1) SA8(kt0 + 2, 1) PH_MID(); MM8(4) PH_END_VM(6); \
        RDA03(1, 0) SB8(kt0 + 2, 1) PH_MID(); MM8(0) PH_END(); \
        RDA47(1, 0) SA8(kt0 + 3, 0) PH_MID(); MM8(4) PH_END(); \
        RDA03(1, 1) SB8(kt0 + 3, 0) PH_MID(); MM8(0) PH_END(); \
        RDA47(1, 1) SA8(kt0 + 3, 1) PH_MID(); MM8(4) PH_END_VM(6); \
    } \
    RDA03(0, 0) SB8((NKTc) - 1, 1) PH_MID(); MM8(0) PH_END(); \
    RDA47(0, 0) PH_MID(); MM8(4) PH_END(); \
    RDA03(0, 1) PH_MID(); MM8(0) PH_END(); \
    RDA47(0, 1) PH_MID(); MM8(4) PH_END_VM(0); \
    RDA03(1, 0) PH_MID(); MM8(0) PH_END(); \
    RDA47(1, 0) PH_MID(); MM8(4) PH_END(); \
    RDA03(1, 1) PH_MID(); MM8(0) PH_END(); \
    RDA47(1, 1) PH_MID(); MM8(4) __builtin_amdgcn_s_setprio(0); __builtin_amdgcn_sched_barrier(0);

// ---------------- GEMM1 (8-phase, persistent): H[lt-rows] = relu(gather(hbf) @ wiT^T) ------
__global__ __launch_bounds__(512, 1) void gemm1_8p(
    const u16* __restrict__ hbf, const u16* __restrict__ wiT, size_t wstride,
    const int* __restrict__ slot_token, const int* __restrict__ counts,
    const u16* __restrict__ zerobuf, u16* __restrict__ Hbuf,
    int p0, int nItems, const int* __restrict__ glist, const int* __restrict__ ngp,
    const int* __restrict__ gslot)
{
    constexpr int KDIM = kD, NTn = kF / 256;
    int tid = threadIdx.x, w = tid >> 6, l = tid & 63;
    int wr = w >> 2, wc = w & 3;
    int fr = l & 15, fq = l >> 4;
    int r0 = w * 32 + (l >> 2), r1 = r0 + 16;
    int clog = (l & 3) ^ ((l >> 3) & 3);
    int sw = (fr >> 1) & 3;

    extern __shared__ __align__(16) u16 lds[];
    u16* Ap = lds;
    u16* Bp = lds + 32768;
    int* slots = (int*)(lds + 65536);
    u16* dA = Ap + w * 1024;
    u16* dB = Bp + w * 1024;
    const u16* rA = Ap + (wr * 128 + fr) * 32 + ((fq ^ sw) << 3);
    const u16* rB = Bp + (wc * 64 + fr) * 32 + ((fq ^ sw) << 3);
    int nblk = gridDim.x;
    int nI = glist ? (*ngp) * NTn : nItems;

    #pragma unroll 1
    for (int i = blockIdx.x; i < nI; i += nblk) {
        int e, nt;
        size_t hrow0;
        if (glist) {
            int lt = i / NTn;
            int gpk = glist[lt];
            nt = i % NTn;
            e = gpk >> 8;
            int rowbase = e * (kB * kC) + (gpk & 255) * 256;
            hrow0 = (size_t)lt * 256;                     // H indexed by queue tile
            if (tid < 256) slots[tid] = gslot[rowbase + tid];
        } else {
            nt = i % NTn;
            int g = i / NTn;
            int mt = g & 1, pem = p0 + (g >> 1);
            e = pem >> 3;
            int b = pem & 7;
            int pair = b * kE + e;
            int cnt = counts[pair];
            if (mt * 256 >= cnt) continue;
            hrow0 = (size_t)(pem - p0) * kC + mt * 256;
            if (tid < 256) {
                int s = slot_token[pair * kC + mt * 256 + tid];
                slots[tid] = (s >= 0) ? ((b << 11) | s) : -1;
            }
        }
        __syncthreads();

        int sl0 = slots[r0], sl1 = slots[r1];
        const u16* sA0 = (sl0 >= 0) ? hbf + (size_t)sl0 * kD + clog * 8 : zerobuf + clog * 8;
        const u16* sA1 = (sl1 >= 0) ? hbf + (size_t)sl1 * kD + clog * 8 : zerobuf + clog * 8;
        const u16* wbase = wiT + (size_t)e * wstride;
        const u16* sB0 = wbase + (size_t)(nt * 256 + r0) * KDIM + clog * 8;
        const u16* sB1 = wbase + (size_t)(nt * 256 + r1) * KDIM + clog * 8;

        f32x4 acc[8][4];
        #pragma unroll
        for (int m = 0; m < 8; m++)
            #pragma unroll
            for (int n = 0; n < 4; n++) acc[m][n] = (f32x4){0.f, 0.f, 0.f, 0.f};
        bf16x8 af[8], bfr[4];

        KLOOP(16, 8)

        int c0 = nt * 256 + wc * 64;
        #pragma unroll
        for (int m = 0; m < 8; m++) {
            #pragma unroll
            for (int j = 0; j < 4; j++) {
                int row = wr * 128 + m * 16 + fq * 4 + j;
                size_t rb = (hrow0 + row) * kF;
                #pragma unroll
                for (int n = 0; n < 4; n++)
                    Hbuf[rb + c0 + n * 16 + fr] = f2bf(fmaxf(acc[m][n][j], 0.f));
            }
        }
        __syncthreads();   // protect slots[] + LDS tiles before next item
    }
}

// ---------------- GEMM2 half-K (tier A): pbuf[kh] = H[lt] @ woT[:, kh-half], bf16 ----------
__global__ __launch_bounds__(512, 1) void gemm2h_8p(
    const u16* __restrict__ Hbuf, const u16* __restrict__ woT,
    const int* __restrict__ glist, const int* __restrict__ ngp, u16* __restrict__ pbuf)
{
    constexpr size_t PH = (size_t)kMaxTiles * 256 * kD;
    int tid = threadIdx.x, w = tid >> 6, l = tid & 63;
    int wr = w >> 2, wc = w & 3;
    int fr = l & 15, fq = l >> 4;
    int r0 = w * 32 + (l >> 2), r1 = r0 + 16;
    int clog = (l & 3) ^ ((l >> 3) & 3);
    int sw = (fr >> 1) & 3;

    extern __shared__ __align__(16) u16 lds[];
    u16* Ap = lds;
    u16* Bp = lds + 32768;
    u16* dA = Ap + w * 1024;
    u16* dB = Bp + w * 1024;
    const u16* rA = Ap + (wr * 128 + fr) * 32 + ((fq ^ sw) << 3);
    const u16* rB = Bp + (wc * 64 + fr) * 32 + ((fq ^ sw) << 3);
    int nblk = gridDim.x;
    int nI = (*ngp) * 8;   // (nt in 0..3) x (kh in 0..1)

    #pragma unroll 1
    for (int i = blockIdx.x; i < nI; i += nblk) {
        int lt = i >> 3;
        int r = i & 7;
        int nt = r >> 1, kh = r & 1;
        int gpk = glist[lt];
        int e = gpk >> 8;
        size_t hrow0 = (size_t)lt * 256;

        const u16* sA0 = Hbuf + (hrow0 + r0) * kF + kh * 2048 + clog * 8;
        const u16* sA1 = Hbuf + (hrow0 + r1) * kF + kh * 2048 + clog * 8;
        const u16* wbase = woT + (size_t)e * kD * kF;
        const u16* sB0 = wbase + (size_t)(nt * 256 + r0) * kF + kh * 2048 + clog * 8;
        const u16* sB1 = wbase + (size_t)(nt * 256 + r1) * kF + kh * 2048 + clog * 8;

        f32x4 acc[8][4];
        #pragma unroll
        for (int m = 0; m < 8; m++)
            #pragma unroll
            for (int n = 0; n < 4; n++) acc[m][n] = (f32x4){0.f, 0.f, 0.f, 0.f};
        bf16x8 af[8], bfr[4];

        KLOOP(32, 16)

        u16* pb = pbuf + (size_t)kh * PH;
        int c0 = nt * 256 + wc * 64;
        #pragma unroll
        for (int m = 0; m < 8; m++) {
            #pragma unroll
            for (int j = 0; j < 4; j++) {
                int row = wr * 128 + m * 16 + fq * 4 + j;
                size_t rb = (hrow0 + row) * kD;
                #pragma unroll
                for (int n = 0; n < 4; n++)
                    pb[rb + c0 + n * 16 + fr] = f2bf(acc[m][n][j]);
            }
        }
        __syncthreads();   // protect LDS tiles before next item
    }
}

// ---------------- epilogue: out[gs] = (p0 + p1) * max_prob, scatter ----------------
__global__ __launch_bounds__(256) void ep_k(
    const int* __restrict__ glist, const int* __restrict__ ngp, const int* __restrict__ gslot,
    const u16* __restrict__ pbuf, const float* __restrict__ maxprob, float* __restrict__ outp)
{
    constexpr size_t PH = (size_t)kMaxTiles * 256 * kD;
    int ng = *ngp;
    size_t total = (size_t)ng * 256 * (kD / 8);
    size_t stride = (size_t)gridDim.x * blockDim.x;
    for (size_t i = (size_t)blockIdx.x * blockDim.x + threadIdx.x; i < total; i += stride) {
        int row = (int)(i / (kD / 8));
        int c8 = (int)(i % (kD / 8)) * 8;
        int lt = row >> 8, r = row & 255;
        int gpk = glist[lt];
        int rowbase = (gpk >> 8) * (kB * kC) + (gpk & 255) * 256;
        int gs = gslot[rowbase + r];
        if (gs < 0) continue;
        float p = maxprob[gs];
        size_t src = (size_t)row * kD + c8;
        uint4 a = *(const uint4*)(pbuf + src);
        uint4 b = *(const uint4*)(pbuf + PH + src);
        const u16* au = (const u16*)&a;
        const u16* bu = (const u16*)&b;
        float o[8];
        #pragma unroll
        for (int k = 0; k < 8; k++) o[k] = (bf2f(au[k]) + bf2f(bu[k])) * p;
        float* dst = outp + (size_t)gs * kD + c8;
        *(float4*)dst = *(const float4*)o;
        *(float4*)(dst + 4) = *(const float4*)(o + 4);
    }
}

// ---------------- GEMM2 full-K (tier B fallback, non-glist) ----------------
__global__ __launch_bounds__(512, 1) void gemm2_8p(
    const u16* __restrict__ Hbuf, const u16* __restrict__ woT, size_t wstride,
    const int* __restrict__ slot_token, const int* __restrict__ counts,
    const float* __restrict__ maxprob, float* __restrict__ outp,
    int p0, int nItems)
{
    constexpr int KDIM = kF, NTn = kD / 256;
    int tid = threadIdx.x, w = tid >> 6, l = tid & 63;
    int wr = w >> 2, wc = w & 3;
    int fr = l & 15, fq = l >> 4;
    int r0 = w * 32 + (l >> 2), r1 = r0 + 16;
    int clog = (l & 3) ^ ((l >> 3) & 3);
    int sw = (fr >> 1) & 3;

    extern __shared__ __align__(16) u16 lds[];
    u16* Ap = lds;
    u16* Bp = lds + 32768;
    int* slots = (int*)(lds + 65536);
    u16* dA = Ap + w * 1024;
    u16* dB = Bp + w * 1024;
    const u16* rA = Ap + (wr * 128 + fr) * 32 + ((fq ^ sw) << 3);
    const u16* rB = Bp + (wc * 64 + fr) * 32 + ((fq ^ sw) << 3);
    int nblk = gridDim.x;

    #pragma unroll 1
    for (int i = blockIdx.x; i < nItems; i += nblk) {
        int nt = i % NTn;
        int g = i / NTn;
        int mt = g & 1, pem = p0 + (g >> 1);
        int e = pem >> 3;
        int b = pem & 7;
        int pair = b * kE + e;
        int cnt = counts[pair];
        if (mt * 256 >= cnt) continue;
        size_t hrow0 = (size_t)(pem - p0) * kC + mt * 256;
        if (tid < 256) {
            int s = slot_token[pair * kC + mt * 256 + tid];
            slots[tid] = (s >= 0) ? ((b << 11) | s) : -1;
        }
        __syncthreads();

        const u16* sA0 = Hbuf + (hrow0 + r0) * kF + clog * 8;
        const u16* sA1 = Hbuf + (hrow0 + r1) * kF + clog * 8;
        const u16* wbase = woT + (size_t)e * wstride;
        const u16* sB0 = wbase + (size_t)(nt * 256 + r0) * KDIM + clog * 8;
        const u16* sB1 = wbase + (size_t)(nt * 256 + r1) * KDIM + clog * 8;

        f32x4 acc[8][4];
        #pragma unroll
        for (int m = 0; m < 8; m++)
            #pragma unroll
            for (int n = 0; n < 4; n++) acc[m][n] = (f32x4){0.f, 0.f, 0.f, 0.f};
        bf16x8 af[8], bfr[4];

        KLOOP(64, 32)

        int c0 = nt * 256 + wc * 64;
        #pragma unroll
        for (int m = 0; m < 8; m++) {
            #pragma unroll
            for (int j = 0; j < 4; j++) {
                int rl = wr * 128 + m * 16 + fq * 4 + j;
                int gs = slots[rl];
                if (gs >= 0) {
                    float p = maxprob[gs];
                    size_t ob = (size_t)gs * kD;
                    #pragma unroll
                    for (int n = 0; n < 4; n++)
                        outp[ob + c0 + n * 16 + fr] = acc[m][n][j] * p;
                }
            }
        }
        __syncthreads();
    }
}

#undef SA8
#undef SB8
#undef RDA03
#undef RDA47
#undef MM8
#undef PH_MID
#undef PH_END
#undef PH_END_VM
#undef KLOOP

// ---------------- naive fp32 fallback (proven) ----------------
__global__ __launch_bounds__(256) void ngemm1_k(
    const float* __restrict__ hidden, const float* __restrict__ wi,
    const int* __restrict__ slot_token, const int* __restrict__ counts,
    float* __restrict__ H, int pair)
{
    int b = pair >> 3, e = pair & 7;
    int cnt = counts[pair];
    int c0 = blockIdx.y * 64, f0 = blockIdx.x * 64;
    if (c0 >= cnt) return;
    __shared__ float As[64][17];
    __shared__ float Bs[16][65];
    __shared__ int slots[64];
    int tx = threadIdx.x, ty = threadIdx.y;
    int tid = ty * 16 + tx;
    if (tid < 64) slots[tid] = slot_token[pair * kC + c0 + tid];
    __syncthreads();
    float acc[4][4];
    #pragma unroll
    for (int i = 0; i < 4; i++)
        #pragma unroll
        for (int j = 0; j < 4; j++) acc[i][j] = 0.f;
    int ar = tid >> 2, ak = (tid & 3) * 4;
    int bd = tid >> 4, bf = (tid & 15) * 4;
    const float* wie = wi + (size_t)e * kD * kF;
    for (int k0 = 0; k0 < kD; k0 += 16) {
        int sl = slots[ar];
        if (sl >= 0) {
            float4 v = *(const float4*)(hidden + (size_t)(b * kS + sl) * kD + k0 + ak);
            As[ar][ak] = v.x; As[ar][ak + 1] = v.y; As[ar][ak + 2] = v.z; As[ar][ak + 3] = v.w;
        } else {
            As[ar][ak] = 0.f; As[ar][ak + 1] = 0.f; As[ar][ak + 2] = 0.f; As[ar][ak + 3] = 0.f;
        }
        float4 wv = *(const float4*)(wie + (size_t)(k0 + bd) * kF + f0 + bf);
        Bs[bd][bf] = wv.x; Bs[bd][bf + 1] = wv.y; Bs[bd][bf + 2] = wv.z; Bs[bd][bf + 3] = wv.w;
        __syncthreads();
        #pragma unroll
        for (int kk = 0; kk < 16; kk++) {
            float a[4], bv[4];
            #pragma unroll
            for (int i = 0; i < 4; i++) a[i] = As[ty * 4 + i][kk];
            #pragma unroll
            for (int j = 0; j < 4; j++) bv[j] = Bs[kk][tx * 4 + j];
            #pragma unroll
            for (int i = 0; i < 4; i++)
                #pragma unroll
                for (int j = 0; j < 4; j++) acc[i][j] += a[i] * bv[j];
        }
        __syncthreads();
    }
    #pragma unroll
    for (int i = 0; i < 4; i++) {
        int row = c0 + ty * 4 + i;
        #pragma unroll
        for (int j = 0; j < 4; j++)
            H[(size_t)row * kF + f0 + tx * 4 + j] = fmaxf(acc[i][j], 0.f);
    }
}

__global__ __launch_bounds__(256) void ngemm2_k(
    const float* __restrict__ H, const float* __restrict__ wo,
    const int* __restrict__ slot_token, const int* __restrict__ counts,
    const float* __restrict__ maxprob, float* __restrict__ outp, int pair)
{
    int b = pair >> 3, e = pair & 7;
    int cnt = counts[pair];
    int c0 = blockIdx.y * 64, d0 = blockIdx.x * 64;
    if (c0 >= cnt) return;
    __shared__ float As[64][17];
    __shared__ float Bs[16][65];
    __shared__ int slots[64];
    int tx = threadIdx.x, ty = threadIdx.y;
    int tid = ty * 16 + tx;
    if (tid < 64) slots[tid] = slot_token[pair * kC + c0 + tid];
    __syncthreads();
    float acc[4][4];
    #pragma unroll
    for (int i = 0; i < 4; i++)
        #pragma unroll
        for (int j = 0; j < 4; j++) acc[i][j] = 0.f;
    int ar = tid >> 2, ak = (tid & 3) * 4;
    int bd = tid >> 4, bf = (tid & 15) * 4;
    const float* woe = wo + (size_t)e * kF * kD;
    for (int k0 = 0; k0 < kF; k0 += 16) {
        float4 v = *(const float4*)(H + (size_t)(c0 + ar) * kF + k0 + ak);
        As[ar][ak] = v.x; As[ar][ak + 1] = v.y; As[ar][ak + 2] = v.z; As[ar][ak + 3] = v.w;
        float4 wv = *(const float4*)(woe + (size_t)(k0 + bd) * kD + d0 + bf);
        Bs[bd][bf] = wv.x; Bs[bd][bf + 1] = wv.y; Bs[bd][bf + 2] = wv.z; Bs[bd][bf + 3] = wv.w;
        __syncthreads();
        #pragma unroll
        for (int kk = 0; kk < 16; kk++) {
            float a[4], bv[4];
            #pragma unroll
            for (int i = 0; i < 4; i++) a[i] = As[ty * 4 + i][kk];
            #pragma unroll
            for (int j = 0; j < 4; j++) bv[j] = Bs[kk][tx * 4 + j];
            #pragma unroll
            for (int i = 0; i < 4; i++)
                #pragma unroll
                for (int j = 0; j < 4; j++) acc[i][j] += a[i] * bv[j];
        }
        __syncthreads();
    }
    #pragma unroll
    for (int i = 0; i < 4; i++) {
        int s = slots[ty * 4 + i];
        if (s >= 0) {
            float p = maxprob[b * kS + s];
            size_t ob = (size_t)(b * kS + s) * kD;
            #pragma unroll
            for (int j = 0; j < 4; j++)
                outp[ob + d0 + tx * 4 + j] = acc[i][j] * p;
        }
    }
}

extern "C" void kernel_launch(void* const* d_in, const int* in_sizes, int n_in,
                              void* d_out, int out_size, void* d_ws, size_t ws_size,
                              hipStream_t stream)
{
    const float* hidden = (const float*)d_in[0];
    const float* rw     = (const float*)d_in[1];
    const float* wi     = (const float*)d_in[2];
    const float* wo     = (const float*)d_in[3];
    float* outp   = (float*)d_out;
    float* logits = outp + (size_t)kB * kS * kD;
    float* expidx = logits + (size_t)kB * kS * kE;

    char* ws = (char*)d_ws;
    size_t off = 0;
    auto alloc = [&](size_t bytes) -> char* {
        char* p = ws + off; off += (bytes + 255) & ~(size_t)255; return p;
    };
    int*   slot_token = (int*)  alloc((size_t)kB * kE * kC * 4);
    int*   counts     = (int*)  alloc((size_t)kB * kE * 4);
    int*   expert_id  = (int*)  alloc((size_t)kB * kS * 4);
    float* maxprob    = (float*)alloc((size_t)kB * kS * 4);
    int*   gslot      = (int*)  alloc((size_t)kE * kB * kC * 4);
    int*   glist      = (int*)  alloc(256 * 4);
    int*   ngp        = (int*)  alloc(256);
    int*   droplist   = (int*)  alloc((size_t)kB * kS * 4);
    int*   ndropp     = (int*)  alloc(256);
    size_t small_off = off;

    const size_t wsz   = (size_t)kD * kF * 2;                   // 8 MiB / expert
    const size_t hsz   = (size_t)kC * kF * 2;                   // 4 MiB / pair (fallback)
    const size_t hbfsz = (size_t)kB * kS * kD * 2;              // 32 MiB
    const size_t Hsz   = (size_t)kMaxTiles * 256 * kF * 2;      // 151 MiB (packed H by tile)
    const size_t psz   = 2 * (size_t)kMaxTiles * 256 * kD * 2;  // 75.5 MiB partials

    hipFuncSetAttribute(reinterpret_cast<const void*>(gemm1_8p),
                        hipFuncAttributeMaxDynamicSharedMemorySize, kSmemBytes);
    hipFuncSetAttribute(reinterpret_cast<const void*>(gemm2h_8p),
                        hipFuncAttributeMaxDynamicSharedMemorySize, kSmemBytes);
    hipFuncSetAttribute(reinterpret_cast<const void*>(gemm2_8p),
                        hipFuncAttributeMaxDynamicSharedMemorySize, kSmemBytes);

    bool tierA = ws_size >= small_off + 2 * kE * wsz + hbfsz + 4096 + Hsz + psz;
    bool tierB = !tierA && ws_size >= small_off + 2 * wsz + hbfsz + 4096 + hsz;

    if (tierA) {
        u16* wiT = (u16*)alloc(kE * wsz);
        u16* woT = (u16*)alloc(kE * wsz);
        u16* hbf = (u16*)alloc(hbfsz);
        u16* zerobuf = (u16*)alloc(4096);
        u16* Hbuf = (u16*)alloc(Hsz);
        u16* pbuf = (u16*)alloc(psz);

        init_k<<<1, 256, 0, stream>>>((uint4*)outp, (uint4*)zerobuf, ndropp, 0);
        router_k<<<kB * kS / 4, 256, 0, stream>>>(hidden, rw, logits, expert_id, maxprob, hbf);
        scan_k<<<kB, 64, 0, stream>>>(expert_id, slot_token, counts, expidx, droplist, ndropp);
        build_k<<<1, 256, 0, stream>>>(counts, slot_token, gslot, glist, ngp);
        zdrop_k<<<512, 256, 0, stream>>>(droplist, ndropp, (float4*)outp);
        transpose_v<<<dim3(kF / 64, kD / 64, kE), 256, 0, stream>>>(wi, wiT, kD, kF);
        transpose_v<<<dim3(kD / 64, kF / 64, kE), 256, 0, stream>>>(wo, woT, kF, kD);

        gemm1_8p<<<256, 512, kSmemBytes, stream>>>(
            hbf, wiT, (size_t)kD * kF, slot_token, counts, zerobuf, Hbuf,
            0, 0, glist, ngp, gslot);
        gemm2h_8p<<<256, 512, kSmemBytes, stream>>>(Hbuf, woT, glist, ngp, pbuf);
        ep_k<<<2048, 256, 0, stream>>>(glist, ngp, gslot, pbuf, maxprob, outp);
    } else if (tierB) {
        u16* wiT = (u16*)alloc(wsz);
        u16* woT = (u16*)alloc(wsz);
        u16* hbf = (u16*)alloc(hbfsz);
        u16* zerobuf = (u16*)alloc(4096);
        int Gb = (int)((ws_size - off) / hsz);
        if (Gb > kB) Gb = kB;
        if (Gb < 1) Gb = 1;
        u16* Hbuf = (u16*)alloc((size_t)Gb * hsz);

        init_k<<<2048, 256, 0, stream>>>((uint4*)outp, (uint4*)zerobuf, ndropp, 1);
        router_k<<<kB * kS / 4, 256, 0, stream>>>(hidden, rw, logits, expert_id, maxprob, hbf);
        scan_k<<<kB, 64, 0, stream>>>(expert_id, slot_token, counts, expidx, nullptr, nullptr);
        for (int e = 0; e < kE; e++) {
            transpose_v<<<dim3(kF / 64, kD / 64, 1), 256, 0, stream>>>(
                wi + (size_t)e * kD * kF, wiT, kD, kF);
            transpose_v<<<dim3(kD / 64, kF / 64, 1), 256, 0, stream>>>(
                wo + (size_t)e * kD * kF, woT, kF, kD);
            for (int b0 = 0; b0 < kB; b0 += Gb) {
                int g = kB - b0 < Gb ? kB - b0 : Gb;
                int p0 = e * 8 + b0;
                gemm1_8p<<<g * 2 * (kF / 256), 512, kSmemBytes, stream>>>(
                    hbf, wiT, 0, slot_token, counts, zerobuf, Hbuf,
                    p0, g * 2 * (kF / 256), nullptr, nullptr, nullptr);
                gemm2_8p<<<g * 2 * (kD / 256), 512, kSmemBytes, stream>>>(
                    Hbuf, woT, 0, slot_token, counts, maxprob, outp, p0, g * 2 * (kD / 256));
            }
        }
    } else {
        float* H = (float*)alloc((size_t)kC * kF * 4);
        init_k<<<2048, 256, 0, stream>>>((uint4*)outp, nullptr, ndropp, 1);
        router_k<<<kB * kS / 4, 256, 0, stream>>>(hidden, rw, logits, expert_id, maxprob, nullptr);
        scan_k<<<kB, 64, 0, stream>>>(expert_id, slot_token, counts, expidx, nullptr, nullptr);
        for (int pair = 0; pair < kB * kE; pair++) {
            ngemm1_k<<<dim3(kF / 64, kC / 64), dim3(16, 16), 0, stream>>>(
                hidden, wi, slot_token, counts, H, pair);
            ngemm2_k<<<dim3(kD / 64, kC / 64), dim3(16, 16), 0, stream>>>(
                H, wo, slot_token, counts, maxprob, outp, pair);
        }
    }
}

// Round 21
// 602.118 us; speedup vs baseline: 1.3854x; 1.3453x over previous
//
#include <hip/hip_runtime.h>
#include <stdint.h>

static constexpr int kB = 8, kS = 2048, kD = 1024, kF = 4096, kE = 8, kC = 512;
static constexpr int kMaxTiles = 72;   // sum_e ceil(tot_e/256) <= 16384/256 + 8

typedef unsigned short u16;
typedef __attribute__((ext_vector_type(8))) short bf16x8;
typedef __attribute__((ext_vector_type(4))) float f32x4;

__device__ __forceinline__ float bf2f(u16 u) {
    union { uint32_t u; float f; } v; v.u = ((uint32_t)u) << 16; return v.f;
}
__device__ __forceinline__ u16 f2bf(float f) {
    union { float f; uint32_t u; } v; v.f = f;
    return (u16)((v.u + 0x7fffu + ((v.u >> 16) & 1u)) >> 16);
}
__device__ __forceinline__ void gload16(const u16* g, u16* l) {
    __builtin_amdgcn_global_load_lds(
        (__attribute__((address_space(1))) void*)(u16*)g,
        (__attribute__((address_space(3))) void*)l, 16, 0, 0);
}

static constexpr int kSmemBytes = 132096;  // A 64KB + B 64KB + slots 1KB

// ---------------- init: zero page, reset ndrop (+ full out sweep for fallback tiers) --------
__global__ void init_k(uint4* __restrict__ outz, uint4* __restrict__ zb,
                       int* __restrict__ ndropp, int sweep) {
    if (blockIdx.x == 0 && threadIdx.x == 0 && ndropp) *ndropp = 0;
    if (blockIdx.x == 0 && zb && threadIdx.x < 256) zb[threadIdx.x] = (uint4){0, 0, 0, 0};
    if (!sweep) return;
    const size_t n = (size_t)kB * kS * kD * 4 / 16;
    size_t stride = (size_t)gridDim.x * blockDim.x;
    for (size_t i = (size_t)blockIdx.x * blockDim.x + threadIdx.x; i < n; i += stride)
        outz[i] = (uint4){0, 0, 0, 0};
}

// ---------------- zero only dropped-token rows of out ----------------
__global__ void zdrop_k(const int* __restrict__ droplist, const int* __restrict__ ndropp,
                        float4* __restrict__ outp) {
    int nd = *ndropp;
    size_t total = (size_t)nd * (kD / 4);
    size_t stride = (size_t)gridDim.x * blockDim.x;
    for (size_t i = (size_t)blockIdx.x * blockDim.x + threadIdx.x; i < total; i += stride) {
        int row = droplist[i >> 8];
        int col = (int)(i & 255);
        outp[(size_t)row * 256 + col] = (float4){0.f, 0.f, 0.f, 0.f};
    }
}

// ---------------- router (fused): fp32 logits + argmax + writes bf16 hidden image ----------
__global__ __launch_bounds__(256) void router_k(
    const float* __restrict__ hidden, const float* __restrict__ rw,
    float* __restrict__ logits_out, int* __restrict__ expert_id, float* __restrict__ maxprob,
    u16* __restrict__ hbf)
{
    int token = blockIdx.x * 4 + (threadIdx.x >> 6);
    int lane = threadIdx.x & 63;
    const float* hrow = hidden + (size_t)token * kD;
    float acc[8] = {0, 0, 0, 0, 0, 0, 0, 0};
    for (int d0 = lane * 4; d0 < kD; d0 += 256) {
        float4 h4 = *(const float4*)(hrow + d0);
        float hv[4] = {h4.x, h4.y, h4.z, h4.w};
        if (hbf) {
            u16 t4[4] = {f2bf(h4.x), f2bf(h4.y), f2bf(h4.z), f2bf(h4.w)};
            *(uint2*)(hbf + (size_t)token * kD + d0) = *(const uint2*)t4;
        }
        #pragma unroll
        for (int j = 0; j < 4; j++) {
            const float* wr = rw + (size_t)(d0 + j) * 8;
            float4 w0 = *(const float4*)wr, w1 = *(const float4*)(wr + 4);
            acc[0] += hv[j] * w0.x; acc[1] += hv[j] * w0.y;
            acc[2] += hv[j] * w0.z; acc[3] += hv[j] * w0.w;
            acc[4] += hv[j] * w1.x; acc[5] += hv[j] * w1.y;
            acc[6] += hv[j] * w1.z; acc[7] += hv[j] * w1.w;
        }
    }
    #pragma unroll
    for (int off = 32; off >= 1; off >>= 1) {
        #pragma unroll
        for (int e = 0; e < 8; e++) acc[e] += __shfl_down(acc[e], off, 64);
    }
    if (lane == 0) {
        float m = acc[0];
        #pragma unroll
        for (int e = 1; e < 8; e++) m = fmaxf(m, acc[e]);
        float ex[8], s = 0.f;
        #pragma unroll
        for (int e = 0; e < 8; e++) { ex[e] = expf(acc[e] - m); s += ex[e]; }
        int best = 0; float bv = -1.f;
        #pragma unroll
        for (int e = 0; e < 8; e++) {
            float p = ex[e] / s;
            if (p > bv) { bv = p; best = e; }
            logits_out[(size_t)token * 8 + e] = acc[e];
        }
        expert_id[token] = best;
        maxprob[token] = bv;
    }
}

// ---------------- capacity scan, PARALLEL (ballot-based stable partition) ----------------
// One block per batch. Stable: chunk-order -> wave-order -> lane-order = token order.
__global__ __launch_bounds__(256) void scan_k(
    const int* __restrict__ expert_id, int* __restrict__ slot_token,
    int* __restrict__ counts, float* __restrict__ expidx_out,
    int* __restrict__ droplist, int* __restrict__ ndropp)
{
    int b = blockIdx.x, tid = threadIdx.x;
    int wv = tid >> 6, ln = tid & 63;
    __shared__ int wcnt[kE][4];   // per-expert per-wave match counts for current chunk
    __shared__ int base[kE];      // running per-expert totals (may exceed kC)
    if (tid < kE) base[tid] = 0;
    __syncthreads();

    for (int c0 = 0; c0 < kS; c0 += 256) {
        int s = c0 + tid;
        int e = expert_id[b * kS + s];
        int myrank = 0;
        #pragma unroll
        for (int j = 0; j < kE; j++) {
            unsigned long long m = __ballot(e == j);
            if (j == e) myrank = __popcll(m & ((1ull << ln) - 1ull));
            if (ln == 0) wcnt[j][wv] = __popcll(m);
        }
        __syncthreads();
        int woff = 0;
        for (int k = 0; k < wv; k++) woff += wcnt[e][k];
        int pos = base[e] + woff + myrank;
        if (pos < kC) {
            slot_token[(b * kE + e) * kC + pos] = s;
            expidx_out[b * kS + s] = (float)e;
        } else {
            expidx_out[b * kS + s] = 0.f;       // dropped -> argmax(zeros)=0
            if (droplist) {
                int di = atomicAdd(ndropp, 1);
                droplist[di] = (b << 11) | s;
            }
        }
        __syncthreads();
        if (tid < kE) {
            int t = 0;
            #pragma unroll
            for (int k = 0; k < 4; k++) t += wcnt[tid][k];
            base[tid] += t;
        }
        __syncthreads();
    }

    if (tid < kE) {
        int cnt = base[tid] < kC ? base[tid] : kC;
        counts[b * kE + tid] = cnt;
    }
    __syncthreads();
    // pad unused slots with -1 (consumed by fallback paths & build_k padding semantics)
    for (int e = 0; e < kE; e++) {
        int cnt = base[e] < kC ? base[e] : kC;
        for (int c = cnt + tid; c < kC; c += 256)
            slot_token[(b * kE + e) * kC + c] = -1;
    }
}

// ---------------- build: pack experts across batches; gslot[e][i] = b*2048+s (-1 pad) ------
__global__ __launch_bounds__(256) void build_k(
    const int* __restrict__ counts, const int* __restrict__ slot_token,
    int* __restrict__ gslot, int* __restrict__ glist, int* __restrict__ ngp)
{
    __shared__ int offs[kE][kB];
    __shared__ int tiles[kE];
    int tid = threadIdx.x;
    if (tid < kE) {
        int e = tid, o = 0;
        #pragma unroll
        for (int b = 0; b < kB; b++) { offs[e][b] = o; o += counts[b * kE + e]; }
        tiles[e] = (o + 255) >> 8;
    }
    __syncthreads();
    for (int e = 0; e < kE; e++) {
        int padded = tiles[e] << 8;
        for (int i = tid; i < padded; i += 256) gslot[e * (kB * kC) + i] = -1;
    }
    __syncthreads();
    for (int e = 0; e < kE; e++)
        for (int b = 0; b < kB; b++) {
            int cnt = counts[b * kE + e], base = offs[e][b];
            for (int c = tid; c < cnt; c += 256)
                gslot[e * (kB * kC) + base + c] = (b << 11) | slot_token[(b * kE + e) * kC + c];
        }
    if (tid == 0) {
        int n = 0;
        for (int e = 0; e < kE; e++)
            for (int t = 0; t < tiles[e]; t++) glist[n++] = (e << 8) | t;
        *ngp = n;
    }
}

// ---------------- vectorized convert-transpose: fp32 [R][Cn] -> bf16 [Cn][R] ----------------
__global__ __launch_bounds__(256) void transpose_v(
    const float* __restrict__ src, u16* __restrict__ dst, int R, int Cn)
{
    __shared__ u16 tl[64][68];
    size_t eo = (size_t)blockIdx.z * R * Cn;
    int c0 = blockIdx.x * 64, r0 = blockIdx.y * 64;
    int t = threadIdx.x;
    int tx = t & 15, ty = t >> 4;
    #pragma unroll
    for (int i = 0; i < 4; i++) {
        int r = ty + 16 * i;
        float4 v = *(const float4*)(src + eo + (size_t)(r0 + r) * Cn + c0 + tx * 4);
        tl[tx * 4 + 0][r] = f2bf(v.x);
        tl[tx * 4 + 1][r] = f2bf(v.y);
        tl[tx * 4 + 2][r] = f2bf(v.z);
        tl[tx * 4 + 3][r] = f2bf(v.w);
    }
    __syncthreads();
    int seg = t & 7, clb = t >> 3;
    #pragma unroll
    for (int ii = 0; ii < 2; ii++) {
        int cl = clb + 32 * ii;
        uint4 v = *(const uint4*)&tl[cl][seg * 8];
        *(uint4*)(dst + eo + (size_t)(c0 + cl) * R + r0 + seg * 8) = v;
    }
}

// ================= shared 8-phase machinery (round-12-proven) =================
#define SA8(kt, kh) { int off_ = (((kt) & 1) << 14) + ((kh) << 13); int go_ = (kt) * 64 + (kh) * 32; \
    gload16(sA0 + go_, dA + off_); gload16(sA1 + go_, dA + off_ + 512); }
#define SB8(kt, kh) { int off_ = (((kt) & 1) << 14) + ((kh) << 13); int go_ = (kt) * 64 + (kh) * 32; \
    gload16(sB0 + go_, dB + off_); gload16(sB1 + go_, dB + off_ + 512); }
#define RDA03(buf, kh) { const u16* a_ = rA + ((buf) << 14) + ((kh) << 13); \
    const u16* b_ = rB + ((buf) << 14) + ((kh) << 13); \
    _Pragma("unroll") for (int m_ = 0; m_ < 4; m_++) af[m_] = *(const bf16x8*)(a_ + m_ * 512); \
    _Pragma("unroll") for (int n_ = 0; n_ < 4; n_++) bfr[n_] = *(const bf16x8*)(b_ + n_ * 512); }
#define RDA47(buf, kh) { const u16* a_ = rA + ((buf) << 14) + ((kh) << 13); \
    _Pragma("unroll") for (int m_ = 4; m_ < 8; m_++) af[m_] = *(const bf16x8*)(a_ + m_ * 512); }
#define MM8(mlo) { _Pragma("unroll") for (int m_ = 0; m_ < 4; m_++) \
    { _Pragma("unroll") for (int n_ = 0; n_ < 4; n_++) \
      acc[(mlo) + m_][n_] = __builtin_amdgcn_mfma_f32_16x16x32_bf16(af[(mlo) + m_], bfr[n_], acc[(mlo) + m_][n_], 0, 0, 0); } }
#define PH_MID() __builtin_amdgcn_sched_barrier(0); __builtin_amdgcn_s_barrier(); \
    asm volatile("s_waitcnt lgkmcnt(0)" ::: "memory"); __builtin_amdgcn_sched_barrier(0); \
    __builtin_amdgcn_s_setprio(1)
#define PH_END() __builtin_amdgcn_s_setprio(0); __builtin_amdgcn_sched_barrier(0); \
    __builtin_amdgcn_s_barrier(); __builtin_amdgcn_sched_barrier(0)
#define PH_END_VM(n) __builtin_amdgcn_s_setprio(0); __builtin_amdgcn_sched_barrier(0); \
    asm volatile("s_waitcnt vmcnt(" #n ")" ::: "memory"); \
    __builtin_amdgcn_s_barrier(); __builtin_amdgcn_sched_barrier(0)

#define KLOOP(NKTc, NIc) \
    SA8(0, 0) SB8(0, 0) SA8(0, 1) SB8(0, 1) SA8(1, 0) SB8(1, 0) SA8(1, 1) \
    asm volatile("s_waitcnt vmcnt(6)" ::: "memory"); \
    __builtin_amdgcn_s_barrier(); \
    __builtin_amdgcn_sched_barrier(0); \
    _Pragma("unroll 1") \
    for (int i2 = 0; i2 < (NIc) - 1; ++i2) { \
        int kt0 = 2 * i2; \
        RDA03(0, 0) SB8(kt0 + 1, 1) PH_MID(); MM8(0) PH_END(); \
        RDA47(0, 0) SA8(kt0 + 2, 0) PH_MID(); MM8(4) PH_END(); \
        RDA03(0, 1) SB8(kt0 + 2, 0) PH_MID(); MM8(0) PH_END(); \
        RDA47(0, 1) SA8(kt0 + 2, 1) PH_MID(); MM8(4) PH_END_VM(6); \
        RDA03(1, 0) SB8(kt0 + 2, 1) PH_MID(); MM8(0) PH_END(); \
        RDA47(1, 0) SA8(kt0 + 3, 0) PH_MID(); MM8(4) PH_END(); \
        RDA03(1, 1) SB8(kt0 + 3, 0) PH_MID(); MM8(0) PH_END(); \
        RDA47(1, 1) SA8(kt0 + 3, 1) PH_MID(); MM8(4) PH_END_VM(6); \
    } \
    RDA03(0, 0) SB8((NKTc) - 1, 1) PH_MID(); MM8(0) PH_END(); \
    RDA47(0, 0) PH_MID(); MM8(4) PH_END(); \
    RDA03(0, 1) PH_MID(); MM8(0) PH_END(); \
    RDA47(0, 1) PH_MID(); MM8(4) PH_END_VM(0); \
    RDA03(1, 0) PH_MID(); MM8(0) PH_END(); \
    RDA47(1, 0) PH_MID(); MM8(4) PH_END(); \
    RDA03(1, 1) PH_MID(); MM8(0) PH_END(); \
    RDA47(1, 1) PH_MID(); MM8(4) __builtin_amdgcn_s_setprio(0); __builtin_amdgcn_sched_barrier(0);

// ---------------- GEMM1 (8-phase, persistent): H[lt-rows] = relu(gather(hbf) @ wiT^T) ------
__global__ __launch_bounds__(512, 1) void gemm1_8p(
    const u16* __restrict__ hbf, const u16* __restrict__ wiT, size_t wstride,
    const int* __restrict__ slot_token, const int* __restrict__ counts,
    const u16* __restrict__ zerobuf, u16* __restrict__ Hbuf,
    int p0, int nItems, const int* __restrict__ glist, const int* __restrict__ ngp,
    const int* __restrict__ gslot)
{
    constexpr int KDIM = kD, NTn = kF / 256;
    int tid = threadIdx.x, w = tid >> 6, l = tid & 63;
    int wr = w >> 2, wc = w & 3;
    int fr = l & 15, fq = l >> 4;
    int r0 = w * 32 + (l >> 2), r1 = r0 + 16;
    int clog = (l & 3) ^ ((l >> 3) & 3);
    int sw = (fr >> 1) & 3;

    extern __shared__ __align__(16) u16 lds[];
    u16* Ap = lds;
    u16* Bp = lds + 32768;
    int* slots = (int*)(lds + 65536);
    u16* dA = Ap + w * 1024;
    u16* dB = Bp + w * 1024;
    const u16* rA = Ap + (wr * 128 + fr) * 32 + ((fq ^ sw) << 3);
    const u16* rB = Bp + (wc * 64 + fr) * 32 + ((fq ^ sw) << 3);
    int nblk = gridDim.x;
    int nI = glist ? (*ngp) * NTn : nItems;

    #pragma unroll 1
    for (int i = blockIdx.x; i < nI; i += nblk) {
        int e, nt;
        size_t hrow0;
        if (glist) {
            int lt = i / NTn;
            int gpk = glist[lt];
            nt = i % NTn;
            e = gpk >> 8;
            int rowbase = e * (kB * kC) + (gpk & 255) * 256;
            hrow0 = (size_t)lt * 256;                     // H indexed by queue tile
            if (tid < 256) slots[tid] = gslot[rowbase + tid];
        } else {
            nt = i % NTn;
            int g = i / NTn;
            int mt = g & 1, pem = p0 + (g >> 1);
            e = pem >> 3;
            int b = pem & 7;
            int pair = b * kE + e;
            int cnt = counts[pair];
            if (mt * 256 >= cnt) continue;
            hrow0 = (size_t)(pem - p0) * kC + mt * 256;
            if (tid < 256) {
                int s = slot_token[pair * kC + mt * 256 + tid];
                slots[tid] = (s >= 0) ? ((b << 11) | s) : -1;
            }
        }
        __syncthreads();

        int sl0 = slots[r0], sl1 = slots[r1];
        const u16* sA0 = (sl0 >= 0) ? hbf + (size_t)sl0 * kD + clog * 8 : zerobuf + clog * 8;
        const u16* sA1 = (sl1 >= 0) ? hbf + (size_t)sl1 * kD + clog * 8 : zerobuf + clog * 8;
        const u16* wbase = wiT + (size_t)e * wstride;
        const u16* sB0 = wbase + (size_t)(nt * 256 + r0) * KDIM + clog * 8;
        const u16* sB1 = wbase + (size_t)(nt * 256 + r1) * KDIM + clog * 8;

        f32x4 acc[8][4];
        #pragma unroll
        for (int m = 0; m < 8; m++)
            #pragma unroll
            for (int n = 0; n < 4; n++) acc[m][n] = (f32x4){0.f, 0.f, 0.f, 0.f};
        bf16x8 af[8], bfr[4];

        KLOOP(16, 8)

        int c0 = nt * 256 + wc * 64;
        #pragma unroll
        for (int m = 0; m < 8; m++) {
            #pragma unroll
            for (int j = 0; j < 4; j++) {
                int row = wr * 128 + m * 16 + fq * 4 + j;
                size_t rb = (hrow0 + row) * kF;
                #pragma unroll
                for (int n = 0; n < 4; n++)
                    Hbuf[rb + c0 + n * 16 + fr] = f2bf(fmaxf(acc[m][n][j], 0.f));
            }
        }
        __syncthreads();   // protect slots[] + LDS tiles before next item
    }
}

// ---------------- GEMM2 half-K (tier A): pbuf[kh] = H[lt] @ woT[:, kh-half], bf16 ----------
__global__ __launch_bounds__(512, 1) void gemm2h_8p(
    const u16* __restrict__ Hbuf, const u16* __restrict__ woT,
    const int* __restrict__ glist, const int* __restrict__ ngp, u16* __restrict__ pbuf)
{
    constexpr size_t PH = (size_t)kMaxTiles * 256 * kD;
    int tid = threadIdx.x, w = tid >> 6, l = tid & 63;
    int wr = w >> 2, wc = w & 3;
    int fr = l & 15, fq = l >> 4;
    int r0 = w * 32 + (l >> 2), r1 = r0 + 16;
    int clog = (l & 3) ^ ((l >> 3) & 3);
    int sw = (fr >> 1) & 3;

    extern __shared__ __align__(16) u16 lds[];
    u16* Ap = lds;
    u16* Bp = lds + 32768;
    u16* dA = Ap + w * 1024;
    u16* dB = Bp + w * 1024;
    const u16* rA = Ap + (wr * 128 + fr) * 32 + ((fq ^ sw) << 3);
    const u16* rB = Bp + (wc * 64 + fr) * 32 + ((fq ^ sw) << 3);
    int nblk = gridDim.x;
    int nI = (*ngp) * 8;   // (nt in 0..3) x (kh in 0..1)

    #pragma unroll 1
    for (int i = blockIdx.x; i < nI; i += nblk) {
        int lt = i >> 3;
        int r = i & 7;
        int nt = r >> 1, kh = r & 1;
        int gpk = glist[lt];
        int e = gpk >> 8;
        size_t hrow0 = (size_t)lt * 256;

        const u16* sA0 = Hbuf + (hrow0 + r0) * kF + kh * 2048 + clog * 8;
        const u16* sA1 = Hbuf + (hrow0 + r1) * kF + kh * 2048 + clog * 8;
        const u16* wbase = woT + (size_t)e * kD * kF;
        const u16* sB0 = wbase + (size_t)(nt * 256 + r0) * kF + kh * 2048 + clog * 8;
        const u16* sB1 = wbase + (size_t)(nt * 256 + r1) * kF + kh * 2048 + clog * 8;

        f32x4 acc[8][4];
        #pragma unroll
        for (int m = 0; m < 8; m++)
            #pragma unroll
            for (int n = 0; n < 4; n++) acc[m][n] = (f32x4){0.f, 0.f, 0.f, 0.f};
        bf16x8 af[8], bfr[4];

        KLOOP(32, 16)

        u16* pb = pbuf + (size_t)kh * PH;
        int c0 = nt * 256 + wc * 64;
        #pragma unroll
        for (int m = 0; m < 8; m++) {
            #pragma unroll
            for (int j = 0; j < 4; j++) {
                int row = wr * 128 + m * 16 + fq * 4 + j;
                size_t rb = (hrow0 + row) * kD;
                #pragma unroll
                for (int n = 0; n < 4; n++)
                    pb[rb + c0 + n * 16 + fr] = f2bf(acc[m][n][j]);
            }
        }
        __syncthreads();   // protect LDS tiles before next item
    }
}

// ---------------- epilogue: out[gs] = (p0 + p1) * max_prob, scatter ----------------
__global__ __launch_bounds__(256) void ep_k(
    const int* __restrict__ glist, const int* __restrict__ ngp, const int* __restrict__ gslot,
    const u16* __restrict__ pbuf, const float* __restrict__ maxprob, float* __restrict__ outp)
{
    constexpr size_t PH = (size_t)kMaxTiles * 256 * kD;
    int ng = *ngp;
    size_t total = (size_t)ng * 256 * (kD / 8);
    size_t stride = (size_t)gridDim.x * blockDim.x;
    for (size_t i = (size_t)blockIdx.x * blockDim.x + threadIdx.x; i < total; i += stride) {
        int row = (int)(i / (kD / 8));
        int c8 = (int)(i % (kD / 8)) * 8;
        int lt = row >> 8, r = row & 255;
        int gpk = glist[lt];
        int rowbase = (gpk >> 8) * (kB * kC) + (gpk & 255) * 256;
        int gs = gslot[rowbase + r];
        if (gs < 0) continue;
        float p = maxprob[gs];
        size_t src = (size_t)row * kD + c8;
        uint4 a = *(const uint4*)(pbuf + src);
        uint4 b = *(const uint4*)(pbuf + PH + src);
        const u16* au = (const u16*)&a;
        const u16* bu = (const u16*)&b;
        float o[8];
        #pragma unroll
        for (int k = 0; k < 8; k++) o[k] = (bf2f(au[k]) + bf2f(bu[k])) * p;
        float* dst = outp + (size_t)gs * kD + c8;
        *(float4*)dst = *(const float4*)o;
        *(float4*)(dst + 4) = *(const float4*)(o + 4);
    }
}

// ---------------- GEMM2 full-K (tier B fallback, non-glist) ----------------
__global__ __launch_bounds__(512, 1) void gemm2_8p(
    const u16* __restrict__ Hbuf, const u16* __restrict__ woT, size_t wstride,
    const int* __restrict__ slot_token, const int* __restrict__ counts,
    const float* __restrict__ maxprob, float* __restrict__ outp,
    int p0, int nItems)
{
    constexpr int KDIM = kF, NTn = kD / 256;
    int tid = threadIdx.x, w = tid >> 6, l = tid & 63;
    int wr = w >> 2, wc = w & 3;
    int fr = l & 15, fq = l >> 4;
    int r0 = w * 32 + (l >> 2), r1 = r0 + 16;
    int clog = (l & 3) ^ ((l >> 3) & 3);
    int sw = (fr >> 1) & 3;

    extern __shared__ __align__(16) u16 lds[];
    u16* Ap = lds;
    u16* Bp = lds + 32768;
    int* slots = (int*)(lds + 65536);
    u16* dA = Ap + w * 1024;
    u16* dB = Bp + w * 1024;
    const u16* rA = Ap + (wr * 128 + fr) * 32 + ((fq ^ sw) << 3);
    const u16* rB = Bp + (wc * 64 + fr) * 32 + ((fq ^ sw) << 3);
    int nblk = gridDim.x;

    #pragma unroll 1
    for (int i = blockIdx.x; i < nItems; i += nblk) {
        int nt = i % NTn;
        int g = i / NTn;
        int mt = g & 1, pem = p0 + (g >> 1);
        int e = pem >> 3;
        int b = pem & 7;
        int pair = b * kE + e;
        int cnt = counts[pair];
        if (mt * 256 >= cnt) continue;
        size_t hrow0 = (size_t)(pem - p0) * kC + mt * 256;
        if (tid < 256) {
            int s = slot_token[pair * kC + mt * 256 + tid];
            slots[tid] = (s >= 0) ? ((b << 11) | s) : -1;
        }
        __syncthreads();

        const u16* sA0 = Hbuf + (hrow0 + r0) * kF + clog * 8;
        const u16* sA1 = Hbuf + (hrow0 + r1) * kF + clog * 8;
        const u16* wbase = woT + (size_t)e * wstride;
        const u16* sB0 = wbase + (size_t)(nt * 256 + r0) * KDIM + clog * 8;
        const u16* sB1 = wbase + (size_t)(nt * 256 + r1) * KDIM + clog * 8;

        f32x4 acc[8][4];
        #pragma unroll
        for (int m = 0; m < 8; m++)
            #pragma unroll
            for (int n = 0; n < 4; n++) acc[m][n] = (f32x4){0.f, 0.f, 0.f, 0.f};
        bf16x8 af[8], bfr[4];

        KLOOP(64, 32)

        int c0 = nt * 256 + wc * 64;
        #pragma unroll
        for (int m = 0; m < 8; m++) {
            #pragma unroll
            for (int j = 0; j < 4; j++) {
                int rl = wr * 128 + m * 16 + fq * 4 + j;
                int gs = slots[rl];
                if (gs >= 0) {
                    float p = maxprob[gs];
                    size_t ob = (size_t)gs * kD;
                    #pragma unroll
                    for (int n = 0; n < 4; n++)
                        outp[ob + c0 + n * 16 + fr] = acc[m][n][j] * p;
                }
            }
        }
        __syncthreads();
    }
}

#undef SA8
#undef SB8
#undef RDA03
#undef RDA47
#undef MM8
#undef PH_MID
#undef PH_END
#undef PH_END_VM
#undef KLOOP

// ---------------- naive fp32 fallback (proven) ----------------
__global__ __launch_bounds__(256) void ngemm1_k(
    const float* __restrict__ hidden, const float* __restrict__ wi,
    const int* __restrict__ slot_token, const int* __restrict__ counts,
    float* __restrict__ H, int pair)
{
    int b = pair >> 3, e = pair & 7;
    int cnt = counts[pair];
    int c0 = blockIdx.y * 64, f0 = blockIdx.x * 64;
    if (c0 >= cnt) return;
    __shared__ float As[64][17];
    __shared__ float Bs[16][65];
    __shared__ int slots[64];
    int tx = threadIdx.x, ty = threadIdx.y;
    int tid = ty * 16 + tx;
    if (tid < 64) slots[tid] = slot_token[pair * kC + c0 + tid];
    __syncthreads();
    float acc[4][4];
    #pragma unroll
    for (int i = 0; i < 4; i++)
        #pragma unroll
        for (int j = 0; j < 4; j++) acc[i][j] = 0.f;
    int ar = tid >> 2, ak = (tid & 3) * 4;
    int bd = tid >> 4, bf = (tid & 15) * 4;
    const float* wie = wi + (size_t)e * kD * kF;
    for (int k0 = 0; k0 < kD; k0 += 16) {
        int sl = slots[ar];
        if (sl >= 0) {
            float4 v = *(const float4*)(hidden + (size_t)(b * kS + sl) * kD + k0 + ak);
            As[ar][ak] = v.x; As[ar][ak + 1] = v.y; As[ar][ak + 2] = v.z; As[ar][ak + 3] = v.w;
        } else {
            As[ar][ak] = 0.f; As[ar][ak + 1] = 0.f; As[ar][ak + 2] = 0.f; As[ar][ak + 3] = 0.f;
        }
        float4 wv = *(const float4*)(wie + (size_t)(k0 + bd) * kF + f0 + bf);
        Bs[bd][bf] = wv.x; Bs[bd][bf + 1] = wv.y; Bs[bd][bf + 2] = wv.z; Bs[bd][bf + 3] = wv.w;
        __syncthreads();
        #pragma unroll
        for (int kk = 0; kk < 16; kk++) {
            float a[4], bv[4];
            #pragma unroll
            for (int i = 0; i < 4; i++) a[i] = As[ty * 4 + i][kk];
            #pragma unroll
            for (int j = 0; j < 4; j++) bv[j] = Bs[kk][tx * 4 + j];
            #pragma unroll
            for (int i = 0; i < 4; i++)
                #pragma unroll
                for (int j = 0; j < 4; j++) acc[i][j] += a[i] * bv[j];
        }
        __syncthreads();
    }
    #pragma unroll
    for (int i = 0; i < 4; i++) {
        int row = c0 + ty * 4 + i;
        #pragma unroll
        for (int j = 0; j < 4; j++)
            H[(size_t)row * kF + f0 + tx * 4 + j] = fmaxf(acc[i][j], 0.f);
    }
}

__global__ __launch_bounds__(256) void ngemm2_k(
    const float* __restrict__ H, const float* __restrict__ wo,
    const int* __restrict__ slot_token, const int* __restrict__ counts,
    const float* __restrict__ maxprob, float* __restrict__ outp, int pair)
{
    int b = pair >> 3, e = pair & 7;
    int cnt = counts[pair];
    int c0 = blockIdx.y * 64, d0 = blockIdx.x * 64;
    if (c0 >= cnt) return;
    __shared__ float As[64][17];
    __shared__ float Bs[16][65];
    __shared__ int slots[64];
    int tx = threadIdx.x, ty = threadIdx.y;
    int tid = ty * 16 + tx;
    if (tid < 64) slots[tid] = slot_token[pair * kC + c0 + tid];
    __syncthreads();
    float acc[4][4];
    #pragma unroll
    for (int i = 0; i < 4; i++)
        #pragma unroll
        for (int j = 0; j < 4; j++) acc[i][j] = 0.f;
    int ar = tid >> 2, ak = (tid & 3) * 4;
    int bd = tid >> 4, bf = (tid & 15) * 4;
    const float* woe = wo + (size_t)e * kF * kD;
    for (int k0 = 0; k0 < kF; k0 += 16) {
        float4 v = *(const float4*)(H + (size_t)(c0 + ar) * kF + k0 + ak);
        As[ar][ak] = v.x; As[ar][ak + 1] = v.y; As[ar][ak + 2] = v.z; As[ar][ak + 3] = v.w;
        float4 wv = *(const float4*)(woe + (size_t)(k0 + bd) * kD + d0 + bf);
        Bs[bd][bf] = wv.x; Bs[bd][bf + 1] = wv.y; Bs[bd][bf + 2] = wv.z; Bs[bd][bf + 3] = wv.w;
        __syncthreads();
        #pragma unroll
        for (int kk = 0; kk < 16; kk++) {
            float a[4], bv[4];
            #pragma unroll
            for (int i = 0; i < 4; i++) a[i] = As[ty * 4 + i][kk];
            #pragma unroll
            for (int j = 0; j < 4; j++) bv[j] = Bs[kk][tx * 4 + j];
            #pragma unroll
            for (int i = 0; i < 4; i++)
                #pragma unroll
                for (int j = 0; j < 4; j++) acc[i][j] += a[i] * bv[j];
        }
        __syncthreads();
    }
    #pragma unroll
    for (int i = 0; i < 4; i++) {
        int s = slots[ty * 4 + i];
        if (s >= 0) {
            float p = maxprob[b * kS + s];
            size_t ob = (size_t)(b * kS + s) * kD;
            #pragma unroll
            for (int j = 0; j < 4; j++)
                outp[ob + d0 + tx * 4 + j] = acc[i][j] * p;
        }
    }
}

extern "C" void kernel_launch(void* const* d_in, const int* in_sizes, int n_in,
                              void* d_out, int out_size, void* d_ws, size_t ws_size,
                              hipStream_t stream)
{
    const float* hidden = (const float*)d_in[0];
    const float* rw     = (const float*)d_in[1];
    const float* wi     = (const float*)d_in[2];
    const float* wo     = (const float*)d_in[3];
    float* outp   = (float*)d_out;
    float* logits = outp + (size_t)kB * kS * kD;
    float* expidx = logits + (size_t)kB * kS * kE;

    char* ws = (char*)d_ws;
    size_t off = 0;
    auto alloc = [&](size_t bytes) -> char* {
        char* p = ws + off; off += (bytes + 255) & ~(size_t)255; return p;
    };
    int*   slot_token = (int*)  alloc((size_t)kB * kE * kC * 4);
    int*   counts     = (int*)  alloc((size_t)kB * kE * 4);
    int*   expert_id  = (int*)  alloc((size_t)kB * kS * 4);
    float* maxprob    = (float*)alloc((size_t)kB * kS * 4);
    int*   gslot      = (int*)  alloc((size_t)kE * kB * kC * 4);
    int*   glist      = (int*)  alloc(256 * 4);
    int*   ngp        = (int*)  alloc(256);
    int*   droplist   = (int*)  alloc((size_t)kB * kS * 4);
    int*   ndropp     = (int*)  alloc(256);
    size_t small_off = off;

    const size_t wsz   = (size_t)kD * kF * 2;                   // 8 MiB / expert
    const size_t hsz   = (size_t)kC * kF * 2;                   // 4 MiB / pair (fallback)
    const size_t hbfsz = (size_t)kB * kS * kD * 2;              // 32 MiB
    const size_t Hsz   = (size_t)kMaxTiles * 256 * kF * 2;      // 151 MiB (packed H by tile)
    const size_t psz   = 2 * (size_t)kMaxTiles * 256 * kD * 2;  // 75.5 MiB partials

    hipFuncSetAttribute(reinterpret_cast<const void*>(gemm1_8p),
                        hipFuncAttributeMaxDynamicSharedMemorySize, kSmemBytes);
    hipFuncSetAttribute(reinterpret_cast<const void*>(gemm2h_8p),
                        hipFuncAttributeMaxDynamicSharedMemorySize, kSmemBytes);
    hipFuncSetAttribute(reinterpret_cast<const void*>(gemm2_8p),
                        hipFuncAttributeMaxDynamicSharedMemorySize, kSmemBytes);

    bool tierA = ws_size >= small_off + 2 * kE * wsz + hbfsz + 4096 + Hsz + psz;
    bool tierB = !tierA && ws_size >= small_off + 2 * wsz + hbfsz + 4096 + hsz;

    if (tierA) {
        u16* wiT = (u16*)alloc(kE * wsz);
        u16* woT = (u16*)alloc(kE * wsz);
        u16* hbf = (u16*)alloc(hbfsz);
        u16* zerobuf = (u16*)alloc(4096);
        u16* Hbuf = (u16*)alloc(Hsz);
        u16* pbuf = (u16*)alloc(psz);

        init_k<<<1, 256, 0, stream>>>((uint4*)outp, (uint4*)zerobuf, ndropp, 0);
        router_k<<<kB * kS / 4, 256, 0, stream>>>(hidden, rw, logits, expert_id, maxprob, hbf);
        scan_k<<<kB, 256, 0, stream>>>(expert_id, slot_token, counts, expidx, droplist, ndropp);
        build_k<<<1, 256, 0, stream>>>(counts, slot_token, gslot, glist, ngp);
        zdrop_k<<<512, 256, 0, stream>>>(droplist, ndropp, (float4*)outp);
        transpose_v<<<dim3(kF / 64, kD / 64, kE), 256, 0, stream>>>(wi, wiT, kD, kF);
        transpose_v<<<dim3(kD / 64, kF / 64, kE), 256, 0, stream>>>(wo, woT, kF, kD);

        gemm1_8p<<<256, 512, kSmemBytes, stream>>>(
            hbf, wiT, (size_t)kD * kF, slot_token, counts, zerobuf, Hbuf,
            0, 0, glist, ngp, gslot);
        gemm2h_8p<<<256, 512, kSmemBytes, stream>>>(Hbuf, woT, glist, ngp, pbuf);
        ep_k<<<2048, 256, 0, stream>>>(glist, ngp, gslot, pbuf, maxprob, outp);
    } else if (tierB) {
        u16* wiT = (u16*)alloc(wsz);
        u16* woT = (u16*)alloc(wsz);
        u16* hbf = (u16*)alloc(hbfsz);
        u16* zerobuf = (u16*)alloc(4096);
        int Gb = (int)((ws_size - off) / hsz);
        if (Gb > kB) Gb = kB;
        if (Gb < 1) Gb = 1;
        u16* Hbuf = (u16*)alloc((size_t)Gb * hsz);

        init_k<<<2048, 256, 0, stream>>>((uint4*)outp, (uint4*)zerobuf, ndropp, 1);
        router_k<<<kB * kS / 4, 256, 0, stream>>>(hidden, rw, logits, expert_id, maxprob, hbf);
        scan_k<<<kB, 256, 0, stream>>>(expert_id, slot_token, counts, expidx, nullptr, nullptr);
        for (int e = 0; e < kE; e++) {
            transpose_v<<<dim3(kF / 64, kD / 64, 1), 256, 0, stream>>>(
                wi + (size_t)e * kD * kF, wiT, kD, kF);
            transpose_v<<<dim3(kD / 64, kF / 64, 1), 256, 0, stream>>>(
                wo + (size_t)e * kD * kF, woT, kF, kD);
            for (int b0 = 0; b0 < kB; b0 += Gb) {
                int g = kB - b0 < Gb ? kB - b0 : Gb;
                int p0 = e * 8 + b0;
                gemm1_8p<<<g * 2 * (kF / 256), 512, kSmemBytes, stream>>>(
                    hbf, wiT, 0, slot_token, counts, zerobuf, Hbuf,
                    p0, g * 2 * (kF / 256), nullptr, nullptr, nullptr);
                gemm2_8p<<<g * 2 * (kD / 256), 512, kSmemBytes, stream>>>(
                    Hbuf, woT, 0, slot_token, counts, maxprob, outp, p0, g * 2 * (kD / 256));
            }
        }
    } else {
        float* H = (float*)alloc((size_t)kC * kF * 4);
        init_k<<<2048, 256, 0, stream>>>((uint4*)outp, nullptr, ndropp, 1);
        router_k<<<kB * kS / 4, 256, 0, stream>>>(hidden, rw, logits, expert_id, maxprob, nullptr);
        scan_k<<<kB, 256, 0, stream>>>(expert_id, slot_token, counts, expidx, nullptr, nullptr);
        for (int pair = 0; pair < kB * kE; pair++) {
            ngemm1_k<<<dim3(kF / 64, kC / 64), dim3(16, 16), 0, stream>>>(
                hidden, wi, slot_token, counts, H, pair);
            ngemm2_k<<<dim3(kD / 64, kC / 64), dim3(16, 16), 0, stream>>>(
                H, wo, slot_token, counts, maxprob, outp, pair);
        }
    }
}